// Round 20
// baseline (244.891 us; speedup 1.0000x reference)
//
#include <hip/hip_runtime.h>

typedef unsigned short u16;
typedef __attribute__((ext_vector_type(8))) short bf16x8;
typedef __attribute__((ext_vector_type(4))) float f32x4;

// ---------- ws layout (float offsets) ----------
enum : int {
  WT1 = 0,          // [27][64]   conv1 weights transposed
  WT2 = 1728,       // [576][64]
  WT3 = 38592,      // [576][64]
  T1  = 75456,      // [9216][64] conv1 out; later bf16 weight frags
  T2  = 665280,     // [9216][64] conv2 out; later GSV
  FEAT= 1255104,    // [9216][64] conv3 out
  PREDP=1844928,    // [3][147456] pre-refine pred planes
  FLAGP=2287296,    // [147456]
  WS_END = 2434752  // 9.74 MB (proven footprint)
};
enum : int { GSVo = T2 };   // [147456][3] grid-sample values (T2 dead after conv3)
// bf16 MFMA weight fragments, u16 offsets relative to (u16*)(ws + T1)
enum : int { HB1o = 0, HB2o = 24576, HB3o = 90112, HB4o = 155648, HB_TOT = 159744 };

#define QTOT 147456

__device__ __forceinline__ u16 f2b(float f){
  union { float f; unsigned int i; } v; v.f = f;
  unsigned int x = v.i;
  x += 0x7fffu + ((x >> 16) & 1u);   // RNE
  return (u16)(x >> 16);
}
__device__ __forceinline__ unsigned cvtpk(float lo, float hi){
  unsigned r; asm("v_cvt_pk_bf16_f32 %0, %1, %2" : "=v"(r) : "v"(lo), "v"(hi)); return r;
}
union Frag { uint4 u; bf16x8 h; };
__device__ __forceinline__ f32x4 MF(bf16x8 a, bf16x8 b, f32x4 c){
  return __builtin_amdgcn_mfma_f32_16x16x32_bf16(a, b, c, 0, 0, 0);
}

// ---------- prep: conv weight transpose ----------
__global__ __launch_bounds__(256) void prep_k(
    const float* __restrict__ ew1, const float* __restrict__ ew2,
    const float* __restrict__ ew3, float* __restrict__ ws)
{
  int t = blockIdx.x * 256 + threadIdx.x;
  if (t < 1728){ int co=t/27,  r=t-co*27;  ws[WT1 + r*64 + co] = ew1[t]; return; } t -= 1728;
  if (t < 36864){ int co=t/576, r=t-co*576; ws[WT2 + r*64 + co] = ew2[t]; return; } t -= 36864;
  if (t < 36864){ int co=t/576, r=t-co*576; ws[WT3 + r*64 + co] = ew3[t]; return; }
}

// ---------- prep_b: heavy-MLP weights -> bf16 MFMA fragment layout ----------
__global__ __launch_bounds__(256) void prep_b(
    const float* __restrict__ wh1, const float* __restrict__ wh2,
    const float* __restrict__ wh3, const float* __restrict__ wh4,
    u16* __restrict__ hb)
{
  int t = blockIdx.x * 256 + threadIdx.x;
  if (t < 24576){   // HB1: 16 nt x 3 kt (K=68 padded to 96)
    int i = t&7, lane = (t>>3)&63, g = t>>9, kt = g%3, nt = g/3;
    int k = kt*32 + (lane>>4)*8 + i, n = nt*16 + (lane&15);
    hb[HB1o + t] = f2b(k < 68 ? wh1[k*256 + n] : 0.f); return;
  } t -= 24576;
  if (t < 65536){   // HB2: 16 nt x 8 kt
    int i = t&7, lane = (t>>3)&63, g = t>>9, kt = g&7, nt = g>>3;
    int k = kt*32 + (lane>>4)*8 + i, n = nt*16 + (lane&15);
    hb[HB2o + t] = f2b(wh2[k*256 + n]); return;
  } t -= 65536;
  if (t < 65536){   // HB3
    int i = t&7, lane = (t>>3)&63, g = t>>9, kt = g&7, nt = g>>3;
    int k = kt*32 + (lane>>4)*8 + i, n = nt*16 + (lane&15);
    hb[HB3o + t] = f2b(wh3[k*256 + n]); return;
  } t -= 65536;
  if (t < 4096){    // HB4: 1 nt (N=3 padded to 16) x 8 kt
    int i = t&7, lane = (t>>3)&63, kt = t>>9;
    int k = kt*32 + (lane>>4)*8 + i, n = lane&15;
    hb[HB4o + t] = f2b(n < 3 ? wh4[k*3 + n] : 0.f); return;
  }
}

// ---------- conv1: 3 -> 64, relu ----------
__global__ __launch_bounds__(256) void conv1_k(const float* __restrict__ lr, const float* __restrict__ wt1,
                                               const float* __restrict__ b1, float* __restrict__ out)
{
  int t  = threadIdx.x;
  int px = blockIdx.x * 4 + (t >> 6);
  int co = t & 63;
  int y = px / 96, x = px - y * 96;
  float acc = b1[co];
  #pragma unroll
  for (int dy = -1; dy <= 1; ++dy){
    int ny = y + dy; if (ny < 0 || ny > 95) continue;
    #pragma unroll
    for (int dx = -1; dx <= 1; ++dx){
      int nx = x + dx; if (nx < 0 || nx > 95) continue;
      int tap = (dy+1)*3 + (dx+1);
      #pragma unroll
      for (int ci = 0; ci < 3; ++ci)
        acc += lr[ci*9216 + ny*96 + nx] * wt1[(ci*9 + tap)*64 + co];
    }
  }
  out[px*64 + co] = fmaxf(acc, 0.f);
}

// ---------- conv 64->64, LDS-staged weight quarter (r17, proven) ----------
__global__ __launch_bounds__(256, 4) void conv64_k(const float* __restrict__ in, const float* __restrict__ wt,
                                                   const float* __restrict__ bias, float* __restrict__ out, int relu)
{
  __shared__ float wL[576*16];   // 36.9 KB
  int t  = threadIdx.x;
  const int coB = blockIdx.y * 16;

  for (int i = t; i < 9216; i += 256)
    wL[i] = wt[(i >> 4) * 64 + coB + (i & 15)];
  __syncthreads();

  int px = blockIdx.x * 64 + (t >> 2);
  int col = (t & 3) * 4;
  int co  = coB + col;
  int y = px / 96, x = px - y * 96;
  float4 acc = *(const float4*)(bias + co);
  #pragma unroll
  for (int dy = -1; dy <= 1; ++dy){
    int ny = y + dy; if (ny < 0 || ny > 95) continue;
    #pragma unroll
    for (int dx = -1; dx <= 1; ++dx){
      int nx = x + dx; if (nx < 0 || nx > 95) continue;
      int tap = (dy+1)*3 + (dx+1);
      const float* ip = in + (ny*96 + nx)*64;
      const float* wp = wL + tap*16 + col;
      #pragma unroll 4
      for (int c4 = 0; c4 < 16; ++c4){
        float4 iv = *(const float4*)(ip + c4*4);
        float4 w0 = *(const float4*)(wp + (c4*4+0)*144);
        float4 w1 = *(const float4*)(wp + (c4*4+1)*144);
        float4 w2 = *(const float4*)(wp + (c4*4+2)*144);
        float4 w3 = *(const float4*)(wp + (c4*4+3)*144);
        acc.x += iv.x*w0.x + iv.y*w1.x + iv.z*w2.x + iv.w*w3.x;
        acc.y += iv.x*w0.y + iv.y*w1.y + iv.z*w2.y + iv.w*w3.y;
        acc.z += iv.x*w0.z + iv.y*w1.z + iv.z*w2.z + iv.w*w3.z;
        acc.w += iv.x*w0.w + iv.y*w1.w + iv.z*w2.w + iv.w*w3.w;
      }
    }
  }
  if (relu){
    acc.x = fmaxf(acc.x, 0.f); acc.y = fmaxf(acc.y, 0.f);
    acc.z = fmaxf(acc.z, 0.f); acc.w = fmaxf(acc.w, 0.f);
  }
  *(float4*)(out + px*64 + co) = acc;
}

// ---------- K1: gather + classifier + light MLP + grid sample (r12 exact) ----------
__global__ __launch_bounds__(256, 2) void cls_light_k(float* __restrict__ ws,
    const float* __restrict__ lr, const float* __restrict__ coord, const float* __restrict__ cell,
    const float* __restrict__ wl1, const float* __restrict__ bl1,
    const float* __restrict__ wl2, const float* __restrict__ bl2,
    const float* __restrict__ wc1, const float* __restrict__ bc1,
    const float* __restrict__ wc2, const float* __restrict__ bc2,
    float* __restrict__ dout)
{
  __shared__ float inpf[128][76];
  __shared__ float wLc1[68*64];
  __shared__ float wLl1[68*64];
  __shared__ float wLc2[128];
  __shared__ float wLl2[192];
  const float* feat = ws + FEAT;
  const int t = threadIdx.x;
  const int q0 = blockIdx.x * 128;

  for (int i = t; i < 4352; i += 256){ wLc1[i] = wc1[i]; wLl1[i] = wl1[i]; }
  if (t < 128) wLc2[t] = wc2[t];
  if (t < 192) wLl2[t] = wl2[t];

  {
    int q = t >> 1, part = t & 1, gq = q0 + q;
    float cy = coord[gq*2+0], cx = coord[gq*2+1];
    int iy = (int)floorf((cy + 1.f) * 0.5f * 96.f); iy = iy < 0 ? 0 : (iy > 95 ? 95 : iy);
    int ix = (int)floorf((cx + 1.f) * 0.5f * 96.f); ix = ix < 0 ? 0 : (ix > 95 ? 95 : ix);
    const float* fp = feat + (iy*96 + ix)*64 + part*32;
    #pragma unroll
    for (int s = 0; s < 8; ++s)
      *(float4*)&inpf[q][part*32 + s*4] = *(const float4*)(fp + s*4);
    if (part == 0){
      float fy = -1.f + (2.f*(float)iy + 1.f) / 96.f;
      float fx = -1.f + (2.f*(float)ix + 1.f) / 96.f;
      inpf[q][64] = (cy - fy) * 96.f;
      inpf[q][65] = (cx - fx) * 96.f;
      inpf[q][66] = cell[gq*2 + 0] * 96.f;
      inpf[q][67] = cell[gq*2 + 1] * 96.f;
    }
  }
  __syncthreads();

  {
    int q = t >> 1, p = t & 1, j0 = p*32;
    float a[32];
    #pragma unroll
    for (int j = 0; j < 32; ++j) a[j] = bc1[j0 + j];
    #pragma unroll 4
    for (int k = 0; k < 68; ++k){
      float xv = inpf[q][k];
      #pragma unroll
      for (int j = 0; j < 32; ++j) a[j] += xv * wLc1[k*64 + j0 + j];
    }
    float l0 = p ? 0.f : bc2[0], l1 = p ? 0.f : bc2[1];
    #pragma unroll
    for (int j = 0; j < 32; ++j){
      float v = fmaxf(a[j], 0.f);
      l0 += v * wLc2[(j0+j)*2]; l1 += v * wLc2[(j0+j)*2 + 1];
    }
    l0 += __shfl_xor(l0, 1); l1 += __shfl_xor(l1, 1);
    if (p == 0){
      float f = (l1 > l0) ? 1.f : 0.f;
      ws[FLAGP + q0 + q] = f; dout[3*QTOT + q0 + q] = f;
    }
  }

  {
    int q = t >> 1, p = t & 1, j0 = p*32;
    float a[32];
    #pragma unroll
    for (int j = 0; j < 32; ++j) a[j] = bl1[j0 + j];
    #pragma unroll 4
    for (int k = 0; k < 68; ++k){
      float xv = inpf[q][k];
      #pragma unroll
      for (int j = 0; j < 32; ++j) a[j] += xv * wLl1[k*64 + j0 + j];
    }
    float o0 = p ? 0.f : bl2[0], o1 = p ? 0.f : bl2[1], o2 = p ? 0.f : bl2[2];
    #pragma unroll
    for (int j = 0; j < 32; ++j){
      float v = fmaxf(a[j], 0.f);
      o0 += v*wLl2[(j0+j)*3]; o1 += v*wLl2[(j0+j)*3+1]; o2 += v*wLl2[(j0+j)*3+2];
    }
    o0 += __shfl_xor(o0, 1); o1 += __shfl_xor(o1, 1); o2 += __shfl_xor(o2, 1);
    if (p == 0){
      int gq = q0 + q;
      float cy = coord[gq*2], cx = coord[gq*2 + 1];
      float fy = fminf(fmaxf((cy + 1.f) * 96.f / 2.f - 0.5f, 0.f), 95.f);
      float fx = fminf(fmaxf((cx + 1.f) * 96.f / 2.f - 0.5f, 0.f), 95.f);
      float y0f = floorf(fy), x0f = floorf(fx);
      float wy = fy - y0f, wx = fx - x0f;
      int y0 = (int)y0f, x0 = (int)x0f;
      int y1 = y0 + 1 > 95 ? 95 : y0 + 1;
      int x1 = x0 + 1 > 95 ? 95 : x0 + 1;
      float oo[3] = {o0, o1, o2};
      #pragma unroll
      for (int c = 0; c < 3; ++c){
        const float* lp = lr + c*9216;
        float v = lp[y0*96+x0]*(1.f-wy)*(1.f-wx) + lp[y0*96+x1]*(1.f-wy)*wx
                + lp[y1*96+x0]*wy*(1.f-wx) + lp[y1*96+x1]*wy*wx;
        ws[GSVo + gq*3 + c] = v;
        ws[PREDP + c*QTOT + gq] = oo[c] + v;
      }
    }
  }
}

// ---------- in-place heavy layer (256->256): wave owns 2 n-tiles x all 128 rows ----------
// Read phase (K-loop over whole buf) -> barrier -> write phase (disjoint slices)
// -> barrier. Per-output-tile MFMA order (kt ascending) identical to r19.
__device__ __forceinline__ void layerIP(char* buf, const uint4* __restrict__ W,
                                        const float* __restrict__ bias,
                                        int wid, int lrow, int lkg, int lane)
{
  f32x4 acc[8][2];
  #pragma unroll
  for (int j = 0; j < 2; ++j){
    float4 bb = *(const float4*)(bias + (wid*2+j)*16 + lkg*4);
    #pragma unroll
    for (int mt = 0; mt < 8; ++mt) acc[mt][j] = f32x4{bb.x, bb.y, bb.z, bb.w};
  }
  #pragma unroll
  for (int kt = 0; kt < 8; ++kt){
    Frag w[2];
    #pragma unroll
    for (int j = 0; j < 2; ++j) w[j].u = W[((wid*2+j)*8 + kt)*64 + lane];
    #pragma unroll
    for (int mt = 0; mt < 8; ++mt){
      int m = mt*16 + lrow;
      Frag a; a.u = *(const uint4*)(buf + ((m*512 + kt*64 + lkg*16) ^ ((m&7)<<4)));
      acc[mt][0] = MF(w[0].h, a.h, acc[mt][0]);
      acc[mt][1] = MF(w[1].h, a.h, acc[mt][1]);
    }
  }
  __syncthreads();   // all reads complete before any write
  #pragma unroll
  for (int mt = 0; mt < 8; ++mt){
    int m = mt*16 + lrow;
    #pragma unroll
    for (int j = 0; j < 2; ++j){
      f32x4 v = acc[mt][j];
      uint2 hw = make_uint2(cvtpk(fmaxf(v[0],0.f), fmaxf(v[1],0.f)),
                            cvtpk(fmaxf(v[2],0.f), fmaxf(v[3],0.f)));
      *(uint2*)(buf + ((m*512 + (wid*2+j)*32 + lkg*8) ^ ((m&7)<<4))) = hw;
    }
  }
  __syncthreads();   // writes visible for next layer's reads
}

// ---------- K2: heavy MLP, 128 queries/block, 8 waves (1m x 8n), in-place buf ----------
__global__ __launch_bounds__(512, 4) void heavy_k(float* __restrict__ ws,
    const float* __restrict__ coord, const float* __restrict__ cell,
    const float* __restrict__ bh1, const float* __restrict__ bh2,
    const float* __restrict__ bh3, const float* __restrict__ bh4)
{
  __shared__ u16 buf[128*256];      // 64KB single buffer
  char* Hb = (char*)buf;

  const float* feat = ws + FEAT;
  const u16* HB = (const u16*)(ws + T1);
  const int t = threadIdx.x;
  const int q0 = blockIdx.x * 128;
  const int lane = t & 63;
  const int wid  = t >> 6;          // 0..7: owns n-tiles wid*2, wid*2+1
  const int lrow = lane & 15, lkg = lane >> 4;

  // ---- heavy layer 1: global gather -> acc (8 mt x 2 nt) -> buf ----
  {
    const uint4* W1 = (const uint4*)(HB + HB1o);
    f32x4 acc[8][2];
    #pragma unroll
    for (int j = 0; j < 2; ++j){
      float4 bb = *(const float4*)(bh1 + (wid*2+j)*16 + lkg*4);
      #pragma unroll
      for (int mt = 0; mt < 8; ++mt) acc[mt][j] = f32x4{bb.x, bb.y, bb.z, bb.w};
    }
    #pragma unroll
    for (int mt = 0; mt < 8; ++mt){
      int m = mt*16 + lrow, gq = q0 + m;
      float cy = coord[gq*2+0], cx = coord[gq*2+1];
      int iy = (int)floorf((cy + 1.f) * 0.5f * 96.f); iy = iy < 0 ? 0 : (iy > 95 ? 95 : iy);
      int ix = (int)floorf((cx + 1.f) * 0.5f * 96.f); ix = ix < 0 ? 0 : (ix > 95 ? 95 : ix);
      const float* fp = feat + (iy*96 + ix)*64 + lkg*8;
      float4 l0 = *(const float4*)(fp +  0), h0 = *(const float4*)(fp +  4);
      float4 l1 = *(const float4*)(fp + 32), h1 = *(const float4*)(fp + 36);
      Frag bf1[3];
      bf1[0].u = make_uint4(cvtpk(l0.x,l0.y), cvtpk(l0.z,l0.w), cvtpk(h0.x,h0.y), cvtpk(h0.z,h0.w));
      bf1[1].u = make_uint4(cvtpk(l1.x,l1.y), cvtpk(l1.z,l1.w), cvtpk(h1.x,h1.y), cvtpk(h1.z,h1.w));
      uint4 z = make_uint4(0,0,0,0);
      if (lkg == 0){
        float fy = -1.f + (2.f*(float)iy + 1.f) / 96.f;
        float fx = -1.f + (2.f*(float)ix + 1.f) / 96.f;
        float r0 = (cy - fy) * 96.f, r1 = (cx - fx) * 96.f;
        float c0 = cell[gq*2 + 0] * 96.f, c1 = cell[gq*2 + 1] * 96.f;
        z.x = cvtpk(r0, r1); z.y = cvtpk(c0, c1);
      }
      bf1[2].u = z;
      #pragma unroll
      for (int kt = 0; kt < 3; ++kt){
        Frag w[2];
        #pragma unroll
        for (int j = 0; j < 2; ++j) w[j].u = W1[((wid*2+j)*3 + kt)*64 + lane];
        acc[mt][0] = MF(w[0].h, bf1[kt].h, acc[mt][0]);
        acc[mt][1] = MF(w[1].h, bf1[kt].h, acc[mt][1]);
      }
    }
    // write phase (no buf reads in L1 -> no pre-barrier needed)
    #pragma unroll
    for (int mt = 0; mt < 8; ++mt){
      int m = mt*16 + lrow;
      #pragma unroll
      for (int j = 0; j < 2; ++j){
        f32x4 v = acc[mt][j];
        uint2 hw = make_uint2(cvtpk(fmaxf(v[0],0.f), fmaxf(v[1],0.f)),
                              cvtpk(fmaxf(v[2],0.f), fmaxf(v[3],0.f)));
        *(uint2*)(Hb + ((m*512 + (wid*2+j)*32 + lkg*8) ^ ((m&7)<<4))) = hw;
      }
    }
  }
  __syncthreads();

  // ---- heavy layers 2, 3: in-place ----
  layerIP(Hb, (const uint4*)(HB + HB2o), bh2, wid, lrow, lkg, lane);
  layerIP(Hb, (const uint4*)(HB + HB3o), bh3, wid, lrow, lkg, lane);

  // ---- heavy layer 4: wave wid handles m-tile wid; hard-only store ----
  {
    const uint4* W4 = (const uint4*)(HB + HB4o);
    f32x4 a4 = f32x4{0.f,0.f,0.f,0.f};
    int m = wid*16 + lrow;
    #pragma unroll
    for (int kt = 0; kt < 8; ++kt){
      Frag w; w.u = W4[kt*64 + lane];
      Frag a; a.u = *(const uint4*)(Hb + ((m*512 + kt*64 + lkg*16) ^ ((m&7)<<4)));
      a4 = MF(w.h, a.h, a4);
    }
    if (lkg == 0){
      int gq = q0 + m;
      if (ws[FLAGP + gq] > 0.5f){
        #pragma unroll
        for (int r = 0; r < 3; ++r)
          ws[PREDP + r*QTOT + gq] = a4[r] + bh4[r] + ws[GSVo + gq*3 + r];
      }
    }
  }
}

// ---------- refinement + f32 store ----------
__global__ __launch_bounds__(256) void refine_k(const float* __restrict__ ws, float* __restrict__ dout)
{
  int q = blockIdx.x * 256 + threadIdx.x;
  const float* predp = ws + PREDP;
  const float* flagp = ws + FLAGP;
  int y = q / 384, x = q - y*384;
  float p0 = predp[q], p1 = predp[QTOT + q], p2 = predp[2*QTOT + q];
  if (y > 0 && y < 383 && x > 0 && x < 383 && flagp[q] == 0.f){
    float fs = 0.f, s0 = 0.f, s1 = 0.f, s2 = 0.f;
    #pragma unroll
    for (int dy = -1; dy <= 1; ++dy){
      #pragma unroll
      for (int dx = -1; dx <= 1; ++dx){
        int nq = q + dy*384 + dx;
        fs += flagp[nq];
        s0 += predp[nq]; s1 += predp[QTOT + nq]; s2 += predp[2*QTOT + nq];
      }
    }
    if (fs > 0.5f){ p0 = s0 / 9.f; p1 = s1 / 9.f; p2 = s2 / 9.f; }
  }
  dout[q*3 + 0] = p0;
  dout[q*3 + 1] = p1;
  dout[q*3 + 2] = p2;
}

extern "C" void kernel_launch(void* const* d_in, const int* in_sizes, int n_in,
                              void* d_out, int out_size, void* d_ws, size_t ws_size,
                              hipStream_t stream)
{
  const float* lr    = (const float*)d_in[0];
  const float* coord = (const float*)d_in[1];
  const float* cell  = (const float*)d_in[2];
  const float* ew1 = (const float*)d_in[3];  const float* eb1 = (const float*)d_in[4];
  const float* ew2 = (const float*)d_in[5];  const float* eb2 = (const float*)d_in[6];
  const float* ew3 = (const float*)d_in[7];  const float* eb3 = (const float*)d_in[8];
  const float* wh1 = (const float*)d_in[9];  const float* bh1 = (const float*)d_in[10];
  const float* wh2 = (const float*)d_in[11]; const float* bh2 = (const float*)d_in[12];
  const float* wh3 = (const float*)d_in[13]; const float* bh3 = (const float*)d_in[14];
  const float* wh4 = (const float*)d_in[15]; const float* bh4 = (const float*)d_in[16];
  const float* wl1 = (const float*)d_in[17]; const float* bl1 = (const float*)d_in[18];
  const float* wl2 = (const float*)d_in[19]; const float* bl2 = (const float*)d_in[20];
  const float* wc1 = (const float*)d_in[21]; const float* bc1 = (const float*)d_in[22];
  const float* wc2 = (const float*)d_in[23]; const float* bc2 = (const float*)d_in[24];
  float* ws  = (float*)d_ws;
  float* out = (float*)d_out;

  prep_k<<<295, 256, 0, stream>>>(ew1, ew2, ew3, ws);
  conv1_k<<<2304, 256, 0, stream>>>(lr, ws + WT1, eb1, ws + T1);
  conv64_k<<<dim3(144,4), 256, 0, stream>>>(ws + T1, ws + WT2, eb2, ws + T2, 1);
  // T1 now dead -> pack heavy weights into it as bf16 fragments
  prep_b<<<624, 256, 0, stream>>>(wh1, wh2, wh3, wh4, (u16*)(ws + T1));
  conv64_k<<<dim3(144,4), 256, 0, stream>>>(ws + T2, ws + WT3, eb3, ws + FEAT, 0);
  // T2 now dead -> GSVo region
  cls_light_k<<<1152, 256, 0, stream>>>(ws, lr, coord, cell,
                                        wl1, bl1, wl2, bl2, wc1, bc1, wc2, bc2, out);
  heavy_k<<<1152, 512, 0, stream>>>(ws, coord, cell, bh1, bh2, bh3, bh4);
  refine_k<<<576, 256, 0, stream>>>(ws, out);
}

// Round 21
// 189.116 us; speedup vs baseline: 1.2949x; 1.2949x over previous
//
#include <hip/hip_runtime.h>

typedef unsigned short u16;
typedef __attribute__((ext_vector_type(8))) short bf16x8;
typedef __attribute__((ext_vector_type(4))) float f32x4;

// ---------- ws layout (float offsets) ----------
enum : int {
  WT1 = 0,          // [27][64]   conv1 weights transposed
  WT2 = 1728,       // [576][64]
  WT3 = 38592,      // [576][64]
  T1  = 75456,      // [9216][64] conv1 out; later bf16 weight frags
  T2  = 665280,     // [9216][64] conv2 out; later GSV
  FEAT= 1255104,    // [9216][64] conv3 out
  PREDP=1844928,    // [3][147456] pre-refine pred planes
  FLAGP=2287296,    // [147456]
  WS_END = 2434752  // 9.74 MB (proven footprint)
};
enum : int { GSVo = T2 };   // [147456][3] grid-sample values (T2 dead after conv3)
// bf16 MFMA weight fragments, u16 offsets relative to (u16*)(ws + T1)
enum : int { HB1o = 0, HB2o = 24576, HB3o = 90112, HB4o = 155648, HB_TOT = 159744 };

#define QTOT 147456

__device__ __forceinline__ u16 f2b(float f){
  union { float f; unsigned int i; } v; v.f = f;
  unsigned int x = v.i;
  x += 0x7fffu + ((x >> 16) & 1u);   // RNE
  return (u16)(x >> 16);
}
__device__ __forceinline__ unsigned cvtpk(float lo, float hi){
  unsigned r; asm("v_cvt_pk_bf16_f32 %0, %1, %2" : "=v"(r) : "v"(lo), "v"(hi)); return r;
}
union Frag { uint4 u; bf16x8 h; };
__device__ __forceinline__ f32x4 MF(bf16x8 a, bf16x8 b, f32x4 c){
  return __builtin_amdgcn_mfma_f32_16x16x32_bf16(a, b, c, 0, 0, 0);
}

// ---------- prep: conv weight transpose ----------
__global__ __launch_bounds__(256) void prep_k(
    const float* __restrict__ ew1, const float* __restrict__ ew2,
    const float* __restrict__ ew3, float* __restrict__ ws)
{
  int t = blockIdx.x * 256 + threadIdx.x;
  if (t < 1728){ int co=t/27,  r=t-co*27;  ws[WT1 + r*64 + co] = ew1[t]; return; } t -= 1728;
  if (t < 36864){ int co=t/576, r=t-co*576; ws[WT2 + r*64 + co] = ew2[t]; return; } t -= 36864;
  if (t < 36864){ int co=t/576, r=t-co*576; ws[WT3 + r*64 + co] = ew3[t]; return; }
}

// ---------- prep_b: heavy-MLP weights -> bf16 MFMA fragment layout ----------
__global__ __launch_bounds__(256) void prep_b(
    const float* __restrict__ wh1, const float* __restrict__ wh2,
    const float* __restrict__ wh3, const float* __restrict__ wh4,
    u16* __restrict__ hb)
{
  int t = blockIdx.x * 256 + threadIdx.x;
  if (t < 24576){   // HB1: 16 nt x 3 kt (K=68 padded to 96)
    int i = t&7, lane = (t>>3)&63, g = t>>9, kt = g%3, nt = g/3;
    int k = kt*32 + (lane>>4)*8 + i, n = nt*16 + (lane&15);
    hb[HB1o + t] = f2b(k < 68 ? wh1[k*256 + n] : 0.f); return;
  } t -= 24576;
  if (t < 65536){   // HB2: 16 nt x 8 kt
    int i = t&7, lane = (t>>3)&63, g = t>>9, kt = g&7, nt = g>>3;
    int k = kt*32 + (lane>>4)*8 + i, n = nt*16 + (lane&15);
    hb[HB2o + t] = f2b(wh2[k*256 + n]); return;
  } t -= 65536;
  if (t < 65536){   // HB3
    int i = t&7, lane = (t>>3)&63, g = t>>9, kt = g&7, nt = g>>3;
    int k = kt*32 + (lane>>4)*8 + i, n = nt*16 + (lane&15);
    hb[HB3o + t] = f2b(wh3[k*256 + n]); return;
  } t -= 65536;
  if (t < 4096){    // HB4: 1 nt (N=3 padded to 16) x 8 kt
    int i = t&7, lane = (t>>3)&63, kt = t>>9;
    int k = kt*32 + (lane>>4)*8 + i, n = lane&15;
    hb[HB4o + t] = f2b(n < 3 ? wh4[k*3 + n] : 0.f); return;
  }
}

// ---------- conv1: 3 -> 64, relu ----------
__global__ __launch_bounds__(256) void conv1_k(const float* __restrict__ lr, const float* __restrict__ wt1,
                                               const float* __restrict__ b1, float* __restrict__ out)
{
  int t  = threadIdx.x;
  int px = blockIdx.x * 4 + (t >> 6);
  int co = t & 63;
  int y = px / 96, x = px - y * 96;
  float acc = b1[co];
  #pragma unroll
  for (int dy = -1; dy <= 1; ++dy){
    int ny = y + dy; if (ny < 0 || ny > 95) continue;
    #pragma unroll
    for (int dx = -1; dx <= 1; ++dx){
      int nx = x + dx; if (nx < 0 || nx > 95) continue;
      int tap = (dy+1)*3 + (dx+1);
      #pragma unroll
      for (int ci = 0; ci < 3; ++ci)
        acc += lr[ci*9216 + ny*96 + nx] * wt1[(ci*9 + tap)*64 + co];
    }
  }
  out[px*64 + co] = fmaxf(acc, 0.f);
}

// ---------- conv 64->64, LDS-staged weight quarter (r17, proven) ----------
__global__ __launch_bounds__(256, 4) void conv64_k(const float* __restrict__ in, const float* __restrict__ wt,
                                                   const float* __restrict__ bias, float* __restrict__ out, int relu)
{
  __shared__ float wL[576*16];   // 36.9 KB
  int t  = threadIdx.x;
  const int coB = blockIdx.y * 16;

  for (int i = t; i < 9216; i += 256)
    wL[i] = wt[(i >> 4) * 64 + coB + (i & 15)];
  __syncthreads();

  int px = blockIdx.x * 64 + (t >> 2);
  int col = (t & 3) * 4;
  int co  = coB + col;
  int y = px / 96, x = px - y * 96;
  float4 acc = *(const float4*)(bias + co);
  #pragma unroll
  for (int dy = -1; dy <= 1; ++dy){
    int ny = y + dy; if (ny < 0 || ny > 95) continue;
    #pragma unroll
    for (int dx = -1; dx <= 1; ++dx){
      int nx = x + dx; if (nx < 0 || nx > 95) continue;
      int tap = (dy+1)*3 + (dx+1);
      const float* ip = in + (ny*96 + nx)*64;
      const float* wp = wL + tap*16 + col;
      #pragma unroll 4
      for (int c4 = 0; c4 < 16; ++c4){
        float4 iv = *(const float4*)(ip + c4*4);
        float4 w0 = *(const float4*)(wp + (c4*4+0)*144);
        float4 w1 = *(const float4*)(wp + (c4*4+1)*144);
        float4 w2 = *(const float4*)(wp + (c4*4+2)*144);
        float4 w3 = *(const float4*)(wp + (c4*4+3)*144);
        acc.x += iv.x*w0.x + iv.y*w1.x + iv.z*w2.x + iv.w*w3.x;
        acc.y += iv.x*w0.y + iv.y*w1.y + iv.z*w2.y + iv.w*w3.y;
        acc.z += iv.x*w0.z + iv.y*w1.z + iv.z*w2.z + iv.w*w3.z;
        acc.w += iv.x*w0.w + iv.y*w1.w + iv.z*w2.w + iv.w*w3.w;
      }
    }
  }
  if (relu){
    acc.x = fmaxf(acc.x, 0.f); acc.y = fmaxf(acc.y, 0.f);
    acc.z = fmaxf(acc.z, 0.f); acc.w = fmaxf(acc.w, 0.f);
  }
  *(float4*)(out + px*64 + co) = acc;
}

// ---------- K1: gather + classifier + light MLP + grid sample (r12 exact) ----------
__global__ __launch_bounds__(256, 2) void cls_light_k(float* __restrict__ ws,
    const float* __restrict__ lr, const float* __restrict__ coord, const float* __restrict__ cell,
    const float* __restrict__ wl1, const float* __restrict__ bl1,
    const float* __restrict__ wl2, const float* __restrict__ bl2,
    const float* __restrict__ wc1, const float* __restrict__ bc1,
    const float* __restrict__ wc2, const float* __restrict__ bc2,
    float* __restrict__ dout)
{
  __shared__ float inpf[128][76];
  __shared__ float wLc1[68*64];
  __shared__ float wLl1[68*64];
  __shared__ float wLc2[128];
  __shared__ float wLl2[192];
  const float* feat = ws + FEAT;
  const int t = threadIdx.x;
  const int q0 = blockIdx.x * 128;

  for (int i = t; i < 4352; i += 256){ wLc1[i] = wc1[i]; wLl1[i] = wl1[i]; }
  if (t < 128) wLc2[t] = wc2[t];
  if (t < 192) wLl2[t] = wl2[t];

  {
    int q = t >> 1, part = t & 1, gq = q0 + q;
    float cy = coord[gq*2+0], cx = coord[gq*2+1];
    int iy = (int)floorf((cy + 1.f) * 0.5f * 96.f); iy = iy < 0 ? 0 : (iy > 95 ? 95 : iy);
    int ix = (int)floorf((cx + 1.f) * 0.5f * 96.f); ix = ix < 0 ? 0 : (ix > 95 ? 95 : ix);
    const float* fp = feat + (iy*96 + ix)*64 + part*32;
    #pragma unroll
    for (int s = 0; s < 8; ++s)
      *(float4*)&inpf[q][part*32 + s*4] = *(const float4*)(fp + s*4);
    if (part == 0){
      float fy = -1.f + (2.f*(float)iy + 1.f) / 96.f;
      float fx = -1.f + (2.f*(float)ix + 1.f) / 96.f;
      inpf[q][64] = (cy - fy) * 96.f;
      inpf[q][65] = (cx - fx) * 96.f;
      inpf[q][66] = cell[gq*2 + 0] * 96.f;
      inpf[q][67] = cell[gq*2 + 1] * 96.f;
    }
  }
  __syncthreads();

  {
    int q = t >> 1, p = t & 1, j0 = p*32;
    float a[32];
    #pragma unroll
    for (int j = 0; j < 32; ++j) a[j] = bc1[j0 + j];
    #pragma unroll 4
    for (int k = 0; k < 68; ++k){
      float xv = inpf[q][k];
      #pragma unroll
      for (int j = 0; j < 32; ++j) a[j] += xv * wLc1[k*64 + j0 + j];
    }
    float l0 = p ? 0.f : bc2[0], l1 = p ? 0.f : bc2[1];
    #pragma unroll
    for (int j = 0; j < 32; ++j){
      float v = fmaxf(a[j], 0.f);
      l0 += v * wLc2[(j0+j)*2]; l1 += v * wLc2[(j0+j)*2 + 1];
    }
    l0 += __shfl_xor(l0, 1); l1 += __shfl_xor(l1, 1);
    if (p == 0){
      float f = (l1 > l0) ? 1.f : 0.f;
      ws[FLAGP + q0 + q] = f; dout[3*QTOT + q0 + q] = f;
    }
  }

  {
    int q = t >> 1, p = t & 1, j0 = p*32;
    float a[32];
    #pragma unroll
    for (int j = 0; j < 32; ++j) a[j] = bl1[j0 + j];
    #pragma unroll 4
    for (int k = 0; k < 68; ++k){
      float xv = inpf[q][k];
      #pragma unroll
      for (int j = 0; j < 32; ++j) a[j] += xv * wLl1[k*64 + j0 + j];
    }
    float o0 = p ? 0.f : bl2[0], o1 = p ? 0.f : bl2[1], o2 = p ? 0.f : bl2[2];
    #pragma unroll
    for (int j = 0; j < 32; ++j){
      float v = fmaxf(a[j], 0.f);
      o0 += v*wLl2[(j0+j)*3]; o1 += v*wLl2[(j0+j)*3+1]; o2 += v*wLl2[(j0+j)*3+2];
    }
    o0 += __shfl_xor(o0, 1); o1 += __shfl_xor(o1, 1); o2 += __shfl_xor(o2, 1);
    if (p == 0){
      int gq = q0 + q;
      float cy = coord[gq*2], cx = coord[gq*2 + 1];
      float fy = fminf(fmaxf((cy + 1.f) * 96.f / 2.f - 0.5f, 0.f), 95.f);
      float fx = fminf(fmaxf((cx + 1.f) * 96.f / 2.f - 0.5f, 0.f), 95.f);
      float y0f = floorf(fy), x0f = floorf(fx);
      float wy = fy - y0f, wx = fx - x0f;
      int y0 = (int)y0f, x0 = (int)x0f;
      int y1 = y0 + 1 > 95 ? 95 : y0 + 1;
      int x1 = x0 + 1 > 95 ? 95 : x0 + 1;
      float oo[3] = {o0, o1, o2};
      #pragma unroll
      for (int c = 0; c < 3; ++c){
        const float* lp = lr + c*9216;
        float v = lp[y0*96+x0]*(1.f-wy)*(1.f-wx) + lp[y0*96+x1]*(1.f-wy)*wx
                + lp[y1*96+x0]*wy*(1.f-wx) + lp[y1*96+x1]*wy*wx;
        ws[GSVo + gq*3 + c] = v;
        ws[PREDP + c*QTOT + gq] = oo[c] + v;
      }
    }
  }
}

// ---------- in-place heavy layer: wave owns 4 m-tiles (64 rows) x 2 n-tiles ----------
// acc[4][2] = 32 f32 (r12-proven accumulator budget); batched w[2][8] preload
// (r12-proven shape). Read phase -> barrier -> disjoint write phase -> barrier.
__device__ __forceinline__ void layerIP(char* buf, const uint4* __restrict__ W,
                                        const float* __restrict__ bias,
                                        int mbase, int nb2, int lrow, int lkg, int lane)
{
  Frag w[2][8];
  #pragma unroll
  for (int j = 0; j < 2; ++j)
    #pragma unroll
    for (int kt = 0; kt < 8; ++kt)
      w[j][kt].u = W[((nb2+j)*8 + kt)*64 + lane];
  f32x4 acc[4][2];
  #pragma unroll
  for (int j = 0; j < 2; ++j){
    float4 bb = *(const float4*)(bias + (nb2+j)*16 + lkg*4);
    #pragma unroll
    for (int mt = 0; mt < 4; ++mt) acc[mt][j] = f32x4{bb.x, bb.y, bb.z, bb.w};
  }
  #pragma unroll
  for (int kt = 0; kt < 8; ++kt){
    #pragma unroll
    for (int mt = 0; mt < 4; ++mt){
      int m = mbase + mt*16 + lrow;
      Frag a; a.u = *(const uint4*)(buf + ((m*512 + kt*64 + lkg*16) ^ ((m&7)<<4)));
      acc[mt][0] = MF(w[0][kt].h, a.h, acc[mt][0]);
      acc[mt][1] = MF(w[1][kt].h, a.h, acc[mt][1]);
    }
  }
  __syncthreads();   // all reads complete before any write
  #pragma unroll
  for (int mt = 0; mt < 4; ++mt){
    int m = mbase + mt*16 + lrow;
    #pragma unroll
    for (int j = 0; j < 2; ++j){
      f32x4 v = acc[mt][j];
      uint2 hw = make_uint2(cvtpk(fmaxf(v[0],0.f), fmaxf(v[1],0.f)),
                            cvtpk(fmaxf(v[2],0.f), fmaxf(v[3],0.f)));
      *(uint2*)(buf + ((m*512 + (nb2+j)*32 + lkg*8) ^ ((m&7)<<4))) = hw;
    }
  }
  __syncthreads();   // writes visible for next layer
}

// ---------- K2: heavy MLP, 128 queries/block, 16 waves (2m x 8n), in-place ----------
__global__ __launch_bounds__(1024, 4) void heavy_k(float* __restrict__ ws,
    const float* __restrict__ coord, const float* __restrict__ cell,
    const float* __restrict__ bh1, const float* __restrict__ bh2,
    const float* __restrict__ bh3, const float* __restrict__ bh4)
{
  __shared__ u16 buf[128*256];      // 64KB single buffer
  char* Hb = (char*)buf;

  const float* feat = ws + FEAT;
  const u16* HB = (const u16*)(ws + T1);
  const int t = threadIdx.x;
  const int q0 = blockIdx.x * 128;
  const int lane = t & 63;
  const int wid  = t >> 6;          // 0..15
  const int lrow = lane & 15, lkg = lane >> 4;
  const int wm = wid >> 3, wn = wid & 7;   // wave grid 2m x 8n
  const int mbase = wm * 64, nb2 = wn * 2;

  // ---- heavy layer 1: global gather -> acc (4 mt x 2 nt) -> buf ----
  {
    const uint4* W1 = (const uint4*)(HB + HB1o);
    Frag w[2][3];
    #pragma unroll
    for (int j = 0; j < 2; ++j)
      #pragma unroll
      for (int kt = 0; kt < 3; ++kt)
        w[j][kt].u = W1[((nb2+j)*3 + kt)*64 + lane];
    f32x4 acc[4][2];
    #pragma unroll
    for (int j = 0; j < 2; ++j){
      float4 bb = *(const float4*)(bh1 + (nb2+j)*16 + lkg*4);
      #pragma unroll
      for (int mt = 0; mt < 4; ++mt) acc[mt][j] = f32x4{bb.x, bb.y, bb.z, bb.w};
    }
    #pragma unroll
    for (int mt = 0; mt < 4; ++mt){
      int m = mbase + mt*16 + lrow, gq = q0 + m;
      float cy = coord[gq*2+0], cx = coord[gq*2+1];
      int iy = (int)floorf((cy + 1.f) * 0.5f * 96.f); iy = iy < 0 ? 0 : (iy > 95 ? 95 : iy);
      int ix = (int)floorf((cx + 1.f) * 0.5f * 96.f); ix = ix < 0 ? 0 : (ix > 95 ? 95 : ix);
      const float* fp = feat + (iy*96 + ix)*64 + lkg*8;
      float4 l0 = *(const float4*)(fp +  0), h0 = *(const float4*)(fp +  4);
      float4 l1 = *(const float4*)(fp + 32), h1 = *(const float4*)(fp + 36);
      Frag bf1[3];
      bf1[0].u = make_uint4(cvtpk(l0.x,l0.y), cvtpk(l0.z,l0.w), cvtpk(h0.x,h0.y), cvtpk(h0.z,h0.w));
      bf1[1].u = make_uint4(cvtpk(l1.x,l1.y), cvtpk(l1.z,l1.w), cvtpk(h1.x,h1.y), cvtpk(h1.z,h1.w));
      uint4 z = make_uint4(0,0,0,0);
      if (lkg == 0){
        float fy = -1.f + (2.f*(float)iy + 1.f) / 96.f;
        float fx = -1.f + (2.f*(float)ix + 1.f) / 96.f;
        float r0 = (cy - fy) * 96.f, r1 = (cx - fx) * 96.f;
        float c0 = cell[gq*2 + 0] * 96.f, c1 = cell[gq*2 + 1] * 96.f;
        z.x = cvtpk(r0, r1); z.y = cvtpk(c0, c1);
      }
      bf1[2].u = z;
      #pragma unroll
      for (int kt = 0; kt < 3; ++kt){
        acc[mt][0] = MF(w[0][kt].h, bf1[kt].h, acc[mt][0]);
        acc[mt][1] = MF(w[1][kt].h, bf1[kt].h, acc[mt][1]);
      }
    }
    #pragma unroll
    for (int mt = 0; mt < 4; ++mt){
      int m = mbase + mt*16 + lrow;
      #pragma unroll
      for (int j = 0; j < 2; ++j){
        f32x4 v = acc[mt][j];
        uint2 hw = make_uint2(cvtpk(fmaxf(v[0],0.f), fmaxf(v[1],0.f)),
                              cvtpk(fmaxf(v[2],0.f), fmaxf(v[3],0.f)));
        *(uint2*)(Hb + ((m*512 + (nb2+j)*32 + lkg*8) ^ ((m&7)<<4))) = hw;
      }
    }
  }
  __syncthreads();

  // ---- heavy layers 2, 3: in-place ----
  layerIP(Hb, (const uint4*)(HB + HB2o), bh2, mbase, nb2, lrow, lkg, lane);
  layerIP(Hb, (const uint4*)(HB + HB3o), bh3, mbase, nb2, lrow, lkg, lane);

  // ---- heavy layer 4: waves 0..7 each handle one m-tile; hard-only store ----
  if (wid < 8){
    const uint4* W4 = (const uint4*)(HB + HB4o);
    Frag w[8];
    #pragma unroll
    for (int kt = 0; kt < 8; ++kt) w[kt].u = W4[kt*64 + lane];
    f32x4 a4 = f32x4{0.f,0.f,0.f,0.f};
    int m = wid*16 + lrow;
    #pragma unroll
    for (int kt = 0; kt < 8; ++kt){
      Frag a; a.u = *(const uint4*)(Hb + ((m*512 + kt*64 + lkg*16) ^ ((m&7)<<4)));
      a4 = MF(w[kt].h, a.h, a4);
    }
    if (lkg == 0){
      int gq = q0 + m;
      if (ws[FLAGP + gq] > 0.5f){
        #pragma unroll
        for (int r = 0; r < 3; ++r)
          ws[PREDP + r*QTOT + gq] = a4[r] + bh4[r] + ws[GSVo + gq*3 + r];
      }
    }
  }
}

// ---------- refinement + f32 store ----------
__global__ __launch_bounds__(256) void refine_k(const float* __restrict__ ws, float* __restrict__ dout)
{
  int q = blockIdx.x * 256 + threadIdx.x;
  const float* predp = ws + PREDP;
  const float* flagp = ws + FLAGP;
  int y = q / 384, x = q - y*384;
  float p0 = predp[q], p1 = predp[QTOT + q], p2 = predp[2*QTOT + q];
  if (y > 0 && y < 383 && x > 0 && x < 383 && flagp[q] == 0.f){
    float fs = 0.f, s0 = 0.f, s1 = 0.f, s2 = 0.f;
    #pragma unroll
    for (int dy = -1; dy <= 1; ++dy){
      #pragma unroll
      for (int dx = -1; dx <= 1; ++dx){
        int nq = q + dy*384 + dx;
        fs += flagp[nq];
        s0 += predp[nq]; s1 += predp[QTOT + nq]; s2 += predp[2*QTOT + nq];
      }
    }
    if (fs > 0.5f){ p0 = s0 / 9.f; p1 = s1 / 9.f; p2 = s2 / 9.f; }
  }
  dout[q*3 + 0] = p0;
  dout[q*3 + 1] = p1;
  dout[q*3 + 2] = p2;
}

extern "C" void kernel_launch(void* const* d_in, const int* in_sizes, int n_in,
                              void* d_out, int out_size, void* d_ws, size_t ws_size,
                              hipStream_t stream)
{
  const float* lr    = (const float*)d_in[0];
  const float* coord = (const float*)d_in[1];
  const float* cell  = (const float*)d_in[2];
  const float* ew1 = (const float*)d_in[3];  const float* eb1 = (const float*)d_in[4];
  const float* ew2 = (const float*)d_in[5];  const float* eb2 = (const float*)d_in[6];
  const float* ew3 = (const float*)d_in[7];  const float* eb3 = (const float*)d_in[8];
  const float* wh1 = (const float*)d_in[9];  const float* bh1 = (const float*)d_in[10];
  const float* wh2 = (const float*)d_in[11]; const float* bh2 = (const float*)d_in[12];
  const float* wh3 = (const float*)d_in[13]; const float* bh3 = (const float*)d_in[14];
  const float* wh4 = (const float*)d_in[15]; const float* bh4 = (const float*)d_in[16];
  const float* wl1 = (const float*)d_in[17]; const float* bl1 = (const float*)d_in[18];
  const float* wl2 = (const float*)d_in[19]; const float* bl2 = (const float*)d_in[20];
  const float* wc1 = (const float*)d_in[21]; const float* bc1 = (const float*)d_in[22];
  const float* wc2 = (const float*)d_in[23]; const float* bc2 = (const float*)d_in[24];
  float* ws  = (float*)d_ws;
  float* out = (float*)d_out;

  prep_k<<<295, 256, 0, stream>>>(ew1, ew2, ew3, ws);
  conv1_k<<<2304, 256, 0, stream>>>(lr, ws + WT1, eb1, ws + T1);
  conv64_k<<<dim3(144,4), 256, 0, stream>>>(ws + T1, ws + WT2, eb2, ws + T2, 1);
  // T1 now dead -> pack heavy weights into it as bf16 fragments
  prep_b<<<624, 256, 0, stream>>>(wh1, wh2, wh3, wh4, (u16*)(ws + T1));
  conv64_k<<<dim3(144,4), 256, 0, stream>>>(ws + T2, ws + WT3, eb3, ws + FEAT, 0);
  // T2 now dead -> GSVo region
  cls_light_k<<<1152, 256, 0, stream>>>(ws, lr, coord, cell,
                                        wl1, bl1, wl2, bl2, wc1, bc1, wc2, bc2, out);
  heavy_k<<<1152, 1024, 0, stream>>>(ws, coord, cell, bh1, bh2, bh3, bh4);
  refine_k<<<576, 256, 0, stream>>>(ws, out);
}

// Round 22
// 175.849 us; speedup vs baseline: 1.3926x; 1.0754x over previous
//
#include <hip/hip_runtime.h>

typedef unsigned short u16;
typedef __attribute__((ext_vector_type(8))) short bf16x8;
typedef __attribute__((ext_vector_type(4))) float f32x4;

// ---------- ws layout (float offsets) ----------
enum : int {
  WT1 = 0,          // [27][64]   conv1 weights transposed
  WT2 = 1728,       // [576][64]
  WT3 = 38592,      // [576][64]
  T1  = 75456,      // [9216][64] conv1 out; later bf16 weight frags
  T2  = 665280,     // [9216][64] conv2 out; later GSV
  FEAT= 1255104,    // [9216][64] conv3 out
  PREDP=1844928,    // [3][147456] pre-refine pred planes
  FLAGP=2287296,    // [147456]
  WS_END = 2434752  // 9.74 MB (proven footprint)
};
enum : int { GSVo = T2 };   // [147456][3] grid-sample values (T2 dead after conv3)
// bf16 weight fragments, u16 offsets relative to (u16*)(ws + T1)
enum : int { HB1o = 0, HB2o = 24576, HB3o = 90112, HB4o = 155648,
             LB1o = 159744, LB2o = 165888, HB_TOT = 166912 };

#define QTOT 147456

__device__ __forceinline__ u16 f2b(float f){
  union { float f; unsigned int i; } v; v.f = f;
  unsigned int x = v.i;
  x += 0x7fffu + ((x >> 16) & 1u);   // RNE
  return (u16)(x >> 16);
}
__device__ __forceinline__ unsigned cvtpk(float lo, float hi){
  unsigned r; asm("v_cvt_pk_bf16_f32 %0, %1, %2" : "=v"(r) : "v"(lo), "v"(hi)); return r;
}
union Frag { uint4 u; bf16x8 h; };
__device__ __forceinline__ f32x4 MF(bf16x8 a, bf16x8 b, f32x4 c){
  return __builtin_amdgcn_mfma_f32_16x16x32_bf16(a, b, c, 0, 0, 0);
}

// ---------- prep: conv weight transpose ----------
__global__ __launch_bounds__(256) void prep_k(
    const float* __restrict__ ew1, const float* __restrict__ ew2,
    const float* __restrict__ ew3, float* __restrict__ ws)
{
  int t = blockIdx.x * 256 + threadIdx.x;
  if (t < 1728){ int co=t/27,  r=t-co*27;  ws[WT1 + r*64 + co] = ew1[t]; return; } t -= 1728;
  if (t < 36864){ int co=t/576, r=t-co*576; ws[WT2 + r*64 + co] = ew2[t]; return; } t -= 36864;
  if (t < 36864){ int co=t/576, r=t-co*576; ws[WT3 + r*64 + co] = ew3[t]; return; }
}

// ---------- prep_b: heavy + light MLP weights -> bf16 MFMA fragment layout ----------
__global__ __launch_bounds__(256) void prep_b(
    const float* __restrict__ wh1, const float* __restrict__ wh2,
    const float* __restrict__ wh3, const float* __restrict__ wh4,
    const float* __restrict__ wl1, const float* __restrict__ wl2,
    u16* __restrict__ hb)
{
  int t = blockIdx.x * 256 + threadIdx.x;
  if (t < 24576){   // HB1: 16 nt x 3 kt (K=68 padded to 96)
    int i = t&7, lane = (t>>3)&63, g = t>>9, kt = g%3, nt = g/3;
    int k = kt*32 + (lane>>4)*8 + i, n = nt*16 + (lane&15);
    hb[HB1o + t] = f2b(k < 68 ? wh1[k*256 + n] : 0.f); return;
  } t -= 24576;
  if (t < 65536){   // HB2: 16 nt x 8 kt
    int i = t&7, lane = (t>>3)&63, g = t>>9, kt = g&7, nt = g>>3;
    int k = kt*32 + (lane>>4)*8 + i, n = nt*16 + (lane&15);
    hb[HB2o + t] = f2b(wh2[k*256 + n]); return;
  } t -= 65536;
  if (t < 65536){   // HB3
    int i = t&7, lane = (t>>3)&63, g = t>>9, kt = g&7, nt = g>>3;
    int k = kt*32 + (lane>>4)*8 + i, n = nt*16 + (lane&15);
    hb[HB3o + t] = f2b(wh3[k*256 + n]); return;
  } t -= 65536;
  if (t < 4096){    // HB4: 1 nt (N=3 padded to 16) x 8 kt
    int i = t&7, lane = (t>>3)&63, kt = t>>9;
    int k = kt*32 + (lane>>4)*8 + i, n = lane&15;
    hb[HB4o + t] = f2b(n < 3 ? wh4[k*3 + n] : 0.f); return;
  } t -= 4096;
  if (t < 6144){    // LB1: 4 nt x 3 kt (K=68 padded to 96), light hidden
    int i = t&7, lane = (t>>3)&63, g = t>>9, kt = g%3, nt = g/3;
    int k = kt*32 + (lane>>4)*8 + i, n = nt*16 + (lane&15);
    hb[LB1o + t] = f2b(k < 68 ? wl1[k*64 + n] : 0.f); return;
  } t -= 6144;
  if (t < 1024){    // LB2: 1 nt (N=3 pad 16) x 2 kt, light out
    int i = t&7, lane = (t>>3)&63, kt = t>>9;
    int k = kt*32 + (lane>>4)*8 + i, n = lane&15;
    hb[LB2o + t] = f2b(n < 3 ? wl2[k*3 + n] : 0.f); return;
  }
}

// ---------- conv1: 3 -> 64, relu ----------
__global__ __launch_bounds__(256) void conv1_k(const float* __restrict__ lr, const float* __restrict__ wt1,
                                               const float* __restrict__ b1, float* __restrict__ out)
{
  int t  = threadIdx.x;
  int px = blockIdx.x * 4 + (t >> 6);
  int co = t & 63;
  int y = px / 96, x = px - y * 96;
  float acc = b1[co];
  #pragma unroll
  for (int dy = -1; dy <= 1; ++dy){
    int ny = y + dy; if (ny < 0 || ny > 95) continue;
    #pragma unroll
    for (int dx = -1; dx <= 1; ++dx){
      int nx = x + dx; if (nx < 0 || nx > 95) continue;
      int tap = (dy+1)*3 + (dx+1);
      #pragma unroll
      for (int ci = 0; ci < 3; ++ci)
        acc += lr[ci*9216 + ny*96 + nx] * wt1[(ci*9 + tap)*64 + co];
    }
  }
  out[px*64 + co] = fmaxf(acc, 0.f);
}

// ---------- conv 64->64, LDS-staged weight quarter (r17, proven) ----------
__global__ __launch_bounds__(256, 4) void conv64_k(const float* __restrict__ in, const float* __restrict__ wt,
                                                   const float* __restrict__ bias, float* __restrict__ out, int relu)
{
  __shared__ float wL[576*16];   // 36.9 KB
  int t  = threadIdx.x;
  const int coB = blockIdx.y * 16;

  for (int i = t; i < 9216; i += 256)
    wL[i] = wt[(i >> 4) * 64 + coB + (i & 15)];
  __syncthreads();

  int px = blockIdx.x * 64 + (t >> 2);
  int col = (t & 3) * 4;
  int co  = coB + col;
  int y = px / 96, x = px - y * 96;
  float4 acc = *(const float4*)(bias + co);
  #pragma unroll
  for (int dy = -1; dy <= 1; ++dy){
    int ny = y + dy; if (ny < 0 || ny > 95) continue;
    #pragma unroll
    for (int dx = -1; dx <= 1; ++dx){
      int nx = x + dx; if (nx < 0 || nx > 95) continue;
      int tap = (dy+1)*3 + (dx+1);
      const float* ip = in + (ny*96 + nx)*64;
      const float* wp = wL + tap*16 + col;
      #pragma unroll 4
      for (int c4 = 0; c4 < 16; ++c4){
        float4 iv = *(const float4*)(ip + c4*4);
        float4 w0 = *(const float4*)(wp + (c4*4+0)*144);
        float4 w1 = *(const float4*)(wp + (c4*4+1)*144);
        float4 w2 = *(const float4*)(wp + (c4*4+2)*144);
        float4 w3 = *(const float4*)(wp + (c4*4+3)*144);
        acc.x += iv.x*w0.x + iv.y*w1.x + iv.z*w2.x + iv.w*w3.x;
        acc.y += iv.x*w0.y + iv.y*w1.y + iv.z*w2.y + iv.w*w3.y;
        acc.z += iv.x*w0.z + iv.y*w1.z + iv.z*w2.z + iv.w*w3.z;
        acc.w += iv.x*w0.w + iv.y*w1.w + iv.z*w2.w + iv.w*w3.w;
      }
    }
  }
  if (relu){
    acc.x = fmaxf(acc.x, 0.f); acc.y = fmaxf(acc.y, 0.f);
    acc.z = fmaxf(acc.z, 0.f); acc.w = fmaxf(acc.w, 0.f);
  }
  *(float4*)(out + px*64 + co) = acc;
}

// ---------- K1: gather + f32 classifier + grid sample (light MLP moved to heavy_k) ----------
__global__ __launch_bounds__(256, 2) void cls_light_k(float* __restrict__ ws,
    const float* __restrict__ lr, const float* __restrict__ coord, const float* __restrict__ cell,
    const float* __restrict__ wc1, const float* __restrict__ bc1,
    const float* __restrict__ wc2, const float* __restrict__ bc2,
    float* __restrict__ dout)
{
  __shared__ float inpf[128][76];
  __shared__ float wLc1[68*64];
  __shared__ float wLc2[128];
  const float* feat = ws + FEAT;
  const int t = threadIdx.x;
  const int q0 = blockIdx.x * 128;

  for (int i = t; i < 4352; i += 256) wLc1[i] = wc1[i];
  if (t < 128) wLc2[t] = wc2[t];

  {
    int q = t >> 1, part = t & 1, gq = q0 + q;
    float cy = coord[gq*2+0], cx = coord[gq*2+1];
    int iy = (int)floorf((cy + 1.f) * 0.5f * 96.f); iy = iy < 0 ? 0 : (iy > 95 ? 95 : iy);
    int ix = (int)floorf((cx + 1.f) * 0.5f * 96.f); ix = ix < 0 ? 0 : (ix > 95 ? 95 : ix);
    const float* fp = feat + (iy*96 + ix)*64 + part*32;
    #pragma unroll
    for (int s = 0; s < 8; ++s)
      *(float4*)&inpf[q][part*32 + s*4] = *(const float4*)(fp + s*4);
    if (part == 0){
      float fy = -1.f + (2.f*(float)iy + 1.f) / 96.f;
      float fx = -1.f + (2.f*(float)ix + 1.f) / 96.f;
      inpf[q][64] = (cy - fy) * 96.f;
      inpf[q][65] = (cx - fx) * 96.f;
      inpf[q][66] = cell[gq*2 + 0] * 96.f;
      inpf[q][67] = cell[gq*2 + 1] * 96.f;
    }
  }
  __syncthreads();

  // ---- classifier (op order bit-identical to r12-r21 — flag path frozen) ----
  {
    int q = t >> 1, p = t & 1, j0 = p*32;
    float a[32];
    #pragma unroll
    for (int j = 0; j < 32; ++j) a[j] = bc1[j0 + j];
    #pragma unroll 4
    for (int k = 0; k < 68; ++k){
      float xv = inpf[q][k];
      #pragma unroll
      for (int j = 0; j < 32; ++j) a[j] += xv * wLc1[k*64 + j0 + j];
    }
    float l0 = p ? 0.f : bc2[0], l1 = p ? 0.f : bc2[1];
    #pragma unroll
    for (int j = 0; j < 32; ++j){
      float v = fmaxf(a[j], 0.f);
      l0 += v * wLc2[(j0+j)*2]; l1 += v * wLc2[(j0+j)*2 + 1];
    }
    l0 += __shfl_xor(l0, 1); l1 += __shfl_xor(l1, 1);
    if (p == 0){
      float f = (l1 > l0) ? 1.f : 0.f;
      ws[FLAGP + q0 + q] = f; dout[3*QTOT + q0 + q] = f;
    }
  }

  // ---- grid sample (op order identical; writes GSVo only) ----
  if ((t & 1) == 0){
    int q = t >> 1, gq = q0 + q;
    float cy = coord[gq*2], cx = coord[gq*2 + 1];
    float fy = fminf(fmaxf((cy + 1.f) * 96.f / 2.f - 0.5f, 0.f), 95.f);
    float fx = fminf(fmaxf((cx + 1.f) * 96.f / 2.f - 0.5f, 0.f), 95.f);
    float y0f = floorf(fy), x0f = floorf(fx);
    float wy = fy - y0f, wx = fx - x0f;
    int y0 = (int)y0f, x0 = (int)x0f;
    int y1 = y0 + 1 > 95 ? 95 : y0 + 1;
    int x1 = x0 + 1 > 95 ? 95 : x0 + 1;
    #pragma unroll
    for (int c = 0; c < 3; ++c){
      const float* lp = lr + c*9216;
      float v = lp[y0*96+x0]*(1.f-wy)*(1.f-wx) + lp[y0*96+x1]*(1.f-wy)*wx
              + lp[y1*96+x0]*wy*(1.f-wx) + lp[y1*96+x1]*wy*wx;
      ws[GSVo + gq*3 + c] = v;
    }
  }
}

// ---------- in-place heavy layer (r21, proven) ----------
__device__ __forceinline__ void layerIP(char* buf, const uint4* __restrict__ W,
                                        const float* __restrict__ bias,
                                        int mbase, int nb2, int lrow, int lkg, int lane)
{
  Frag w[2][8];
  #pragma unroll
  for (int j = 0; j < 2; ++j)
    #pragma unroll
    for (int kt = 0; kt < 8; ++kt)
      w[j][kt].u = W[((nb2+j)*8 + kt)*64 + lane];
  f32x4 acc[4][2];
  #pragma unroll
  for (int j = 0; j < 2; ++j){
    float4 bb = *(const float4*)(bias + (nb2+j)*16 + lkg*4);
    #pragma unroll
    for (int mt = 0; mt < 4; ++mt) acc[mt][j] = f32x4{bb.x, bb.y, bb.z, bb.w};
  }
  #pragma unroll
  for (int kt = 0; kt < 8; ++kt){
    #pragma unroll
    for (int mt = 0; mt < 4; ++mt){
      int m = mbase + mt*16 + lrow;
      Frag a; a.u = *(const uint4*)(buf + ((m*512 + kt*64 + lkg*16) ^ ((m&7)<<4)));
      acc[mt][0] = MF(w[0][kt].h, a.h, acc[mt][0]);
      acc[mt][1] = MF(w[1][kt].h, a.h, acc[mt][1]);
    }
  }
  __syncthreads();
  #pragma unroll
  for (int mt = 0; mt < 4; ++mt){
    int m = mbase + mt*16 + lrow;
    #pragma unroll
    for (int j = 0; j < 2; ++j){
      f32x4 v = acc[mt][j];
      uint2 hw = make_uint2(cvtpk(fmaxf(v[0],0.f), fmaxf(v[1],0.f)),
                            cvtpk(fmaxf(v[2],0.f), fmaxf(v[3],0.f)));
      *(uint2*)(buf + ((m*512 + (nb2+j)*32 + lkg*8) ^ ((m&7)<<4))) = hw;
    }
  }
  __syncthreads();
}

// ---------- K2: heavy MLP + light MLP, 128 queries/block, 16 waves ----------
__global__ __launch_bounds__(1024, 4) void heavy_k(float* __restrict__ ws,
    const float* __restrict__ coord, const float* __restrict__ cell,
    const float* __restrict__ bh1, const float* __restrict__ bh2,
    const float* __restrict__ bh3, const float* __restrict__ bh4,
    const float* __restrict__ bl1, const float* __restrict__ bl2)
{
  __shared__ u16 buf[128*256];      // 64KB heavy activations
  __shared__ u16 lbuf[128*64];      // 16KB light hidden
  char* Hb = (char*)buf;
  char* Lb = (char*)lbuf;

  const float* feat = ws + FEAT;
  const u16* HB = (const u16*)(ws + T1);
  const int t = threadIdx.x;
  const int q0 = blockIdx.x * 128;
  const int lane = t & 63;
  const int wid  = t >> 6;          // 0..15
  const int lrow = lane & 15, lkg = lane >> 4;
  const int wm = wid >> 3, wn = wid & 7;   // wave grid 2m x 8n
  const int mbase = wm * 64, nb2 = wn * 2;

  // ---- heavy layer 1: global gather -> acc (4 mt x 2 nt) -> buf ----
  {
    const uint4* W1 = (const uint4*)(HB + HB1o);
    Frag w[2][3];
    #pragma unroll
    for (int j = 0; j < 2; ++j)
      #pragma unroll
      for (int kt = 0; kt < 3; ++kt)
        w[j][kt].u = W1[((nb2+j)*3 + kt)*64 + lane];
    f32x4 acc[4][2];
    #pragma unroll
    for (int j = 0; j < 2; ++j){
      float4 bb = *(const float4*)(bh1 + (nb2+j)*16 + lkg*4);
      #pragma unroll
      for (int mt = 0; mt < 4; ++mt) acc[mt][j] = f32x4{bb.x, bb.y, bb.z, bb.w};
    }
    #pragma unroll
    for (int mt = 0; mt < 4; ++mt){
      int m = mbase + mt*16 + lrow, gq = q0 + m;
      float cy = coord[gq*2+0], cx = coord[gq*2+1];
      int iy = (int)floorf((cy + 1.f) * 0.5f * 96.f); iy = iy < 0 ? 0 : (iy > 95 ? 95 : iy);
      int ix = (int)floorf((cx + 1.f) * 0.5f * 96.f); ix = ix < 0 ? 0 : (ix > 95 ? 95 : ix);
      const float* fp = feat + (iy*96 + ix)*64 + lkg*8;
      float4 l0 = *(const float4*)(fp +  0), h0 = *(const float4*)(fp +  4);
      float4 l1 = *(const float4*)(fp + 32), h1 = *(const float4*)(fp + 36);
      Frag bf1[3];
      bf1[0].u = make_uint4(cvtpk(l0.x,l0.y), cvtpk(l0.z,l0.w), cvtpk(h0.x,h0.y), cvtpk(h0.z,h0.w));
      bf1[1].u = make_uint4(cvtpk(l1.x,l1.y), cvtpk(l1.z,l1.w), cvtpk(h1.x,h1.y), cvtpk(h1.z,h1.w));
      uint4 z = make_uint4(0,0,0,0);
      if (lkg == 0){
        float fy = -1.f + (2.f*(float)iy + 1.f) / 96.f;
        float fx = -1.f + (2.f*(float)ix + 1.f) / 96.f;
        float r0 = (cy - fy) * 96.f, r1 = (cx - fx) * 96.f;
        float c0 = cell[gq*2 + 0] * 96.f, c1 = cell[gq*2 + 1] * 96.f;
        z.x = cvtpk(r0, r1); z.y = cvtpk(c0, c1);
      }
      bf1[2].u = z;
      #pragma unroll
      for (int kt = 0; kt < 3; ++kt){
        acc[mt][0] = MF(w[0][kt].h, bf1[kt].h, acc[mt][0]);
        acc[mt][1] = MF(w[1][kt].h, bf1[kt].h, acc[mt][1]);
      }
    }
    #pragma unroll
    for (int mt = 0; mt < 4; ++mt){
      int m = mbase + mt*16 + lrow;
      #pragma unroll
      for (int j = 0; j < 2; ++j){
        f32x4 v = acc[mt][j];
        uint2 hw = make_uint2(cvtpk(fmaxf(v[0],0.f), fmaxf(v[1],0.f)),
                              cvtpk(fmaxf(v[2],0.f), fmaxf(v[3],0.f)));
        *(uint2*)(Hb + ((m*512 + (nb2+j)*32 + lkg*8) ^ ((m&7)<<4))) = hw;
      }
    }
  }
  __syncthreads();

  // ---- heavy layers 2, 3: in-place ----
  layerIP(Hb, (const uint4*)(HB + HB2o), bh2, mbase, nb2, lrow, lkg, lane);
  layerIP(Hb, (const uint4*)(HB + HB3o), bh3, mbase, nb2, lrow, lkg, lane);

  // ---- concurrent: waves 0-7 heavy L4 (hard preds); waves 8-15 light hidden ----
  if (wid < 8){
    const uint4* W4 = (const uint4*)(HB + HB4o);
    Frag w[8];
    #pragma unroll
    for (int kt = 0; kt < 8; ++kt) w[kt].u = W4[kt*64 + lane];
    f32x4 a4 = f32x4{0.f,0.f,0.f,0.f};
    int m = wid*16 + lrow;
    #pragma unroll
    for (int kt = 0; kt < 8; ++kt){
      Frag a; a.u = *(const uint4*)(Hb + ((m*512 + kt*64 + lkg*16) ^ ((m&7)<<4)));
      a4 = MF(w[kt].h, a.h, a4);
    }
    if (lkg == 0){
      int gq = q0 + m;
      if (ws[FLAGP + gq] > 0.5f){
        #pragma unroll
        for (int r = 0; r < 3; ++r)
          ws[PREDP + r*QTOT + gq] = a4[r] + bh4[r] + ws[GSVo + gq*3 + r];
      }
    }
  } else {
    // light hidden: wave (wid-8) handles 16 rows; all 4 n-tiles
    const uint4* WL1 = (const uint4*)(HB + LB1o);
    int m = (wid - 8)*16 + lrow, gq = q0 + m;
    float cy = coord[gq*2+0], cx = coord[gq*2+1];
    int iy = (int)floorf((cy + 1.f) * 0.5f * 96.f); iy = iy < 0 ? 0 : (iy > 95 ? 95 : iy);
    int ix = (int)floorf((cx + 1.f) * 0.5f * 96.f); ix = ix < 0 ? 0 : (ix > 95 ? 95 : ix);
    const float* fp = feat + (iy*96 + ix)*64 + lkg*8;
    float4 l0 = *(const float4*)(fp +  0), h0 = *(const float4*)(fp +  4);
    float4 l1 = *(const float4*)(fp + 32), h1 = *(const float4*)(fp + 36);
    Frag bf1[3];
    bf1[0].u = make_uint4(cvtpk(l0.x,l0.y), cvtpk(l0.z,l0.w), cvtpk(h0.x,h0.y), cvtpk(h0.z,h0.w));
    bf1[1].u = make_uint4(cvtpk(l1.x,l1.y), cvtpk(l1.z,l1.w), cvtpk(h1.x,h1.y), cvtpk(h1.z,h1.w));
    uint4 z = make_uint4(0,0,0,0);
    if (lkg == 0){
      float fy = -1.f + (2.f*(float)iy + 1.f) / 96.f;
      float fx = -1.f + (2.f*(float)ix + 1.f) / 96.f;
      float r0 = (cy - fy) * 96.f, r1 = (cx - fx) * 96.f;
      float c0 = cell[gq*2 + 0] * 96.f, c1 = cell[gq*2 + 1] * 96.f;
      z.x = cvtpk(r0, r1); z.y = cvtpk(c0, c1);
    }
    bf1[2].u = z;
    f32x4 lacc[4];
    #pragma unroll
    for (int j = 0; j < 4; ++j){
      float4 bb = *(const float4*)(bl1 + j*16 + lkg*4);
      lacc[j] = f32x4{bb.x, bb.y, bb.z, bb.w};
    }
    #pragma unroll
    for (int kt = 0; kt < 3; ++kt)
      #pragma unroll
      for (int j = 0; j < 4; ++j){
        Frag w; w.u = WL1[(j*3 + kt)*64 + lane];
        lacc[j] = MF(w.h, bf1[kt].h, lacc[j]);
      }
    #pragma unroll
    for (int j = 0; j < 4; ++j){
      f32x4 v = lacc[j];
      uint2 hw = make_uint2(cvtpk(fmaxf(v[0],0.f), fmaxf(v[1],0.f)),
                            cvtpk(fmaxf(v[2],0.f), fmaxf(v[3],0.f)));
      *(uint2*)(Lb + ((m*128 + j*32 + lkg*8) ^ ((m&7)<<4))) = hw;
    }
  }
  __syncthreads();

  // ---- light out: waves 8-15, easy-only store ----
  if (wid >= 8){
    const uint4* WL2 = (const uint4*)(HB + LB2o);
    int m = (wid - 8)*16 + lrow, gq = q0 + m;
    f32x4 la = f32x4{0.f,0.f,0.f,0.f};
    #pragma unroll
    for (int kt = 0; kt < 2; ++kt){
      Frag w; w.u = WL2[kt*64 + lane];
      Frag a; a.u = *(const uint4*)(Lb + ((m*128 + kt*64 + lkg*16) ^ ((m&7)<<4)));
      la = MF(w.h, a.h, la);
    }
    if (lkg == 0 && ws[FLAGP + gq] <= 0.5f){
      #pragma unroll
      for (int r = 0; r < 3; ++r)
        ws[PREDP + r*QTOT + gq] = la[r] + bl2[r] + ws[GSVo + gq*3 + r];
    }
  }
}

// ---------- refinement + f32 store ----------
__global__ __launch_bounds__(256) void refine_k(const float* __restrict__ ws, float* __restrict__ dout)
{
  int q = blockIdx.x * 256 + threadIdx.x;
  const float* predp = ws + PREDP;
  const float* flagp = ws + FLAGP;
  int y = q / 384, x = q - y*384;
  float p0 = predp[q], p1 = predp[QTOT + q], p2 = predp[2*QTOT + q];
  if (y > 0 && y < 383 && x > 0 && x < 383 && flagp[q] == 0.f){
    float fs = 0.f, s0 = 0.f, s1 = 0.f, s2 = 0.f;
    #pragma unroll
    for (int dy = -1; dy <= 1; ++dy){
      #pragma unroll
      for (int dx = -1; dx <= 1; ++dx){
        int nq = q + dy*384 + dx;
        fs += flagp[nq];
        s0 += predp[nq]; s1 += predp[QTOT + nq]; s2 += predp[2*QTOT + nq];
      }
    }
    if (fs > 0.5f){ p0 = s0 / 9.f; p1 = s1 / 9.f; p2 = s2 / 9.f; }
  }
  dout[q*3 + 0] = p0;
  dout[q*3 + 1] = p1;
  dout[q*3 + 2] = p2;
}

extern "C" void kernel_launch(void* const* d_in, const int* in_sizes, int n_in,
                              void* d_out, int out_size, void* d_ws, size_t ws_size,
                              hipStream_t stream)
{
  const float* lr    = (const float*)d_in[0];
  const float* coord = (const float*)d_in[1];
  const float* cell  = (const float*)d_in[2];
  const float* ew1 = (const float*)d_in[3];  const float* eb1 = (const float*)d_in[4];
  const float* ew2 = (const float*)d_in[5];  const float* eb2 = (const float*)d_in[6];
  const float* ew3 = (const float*)d_in[7];  const float* eb3 = (const float*)d_in[8];
  const float* wh1 = (const float*)d_in[9];  const float* bh1 = (const float*)d_in[10];
  const float* wh2 = (const float*)d_in[11]; const float* bh2 = (const float*)d_in[12];
  const float* wh3 = (const float*)d_in[13]; const float* bh3 = (const float*)d_in[14];
  const float* wh4 = (const float*)d_in[15]; const float* bh4 = (const float*)d_in[16];
  const float* wl1 = (const float*)d_in[17]; const float* bl1 = (const float*)d_in[18];
  const float* wl2 = (const float*)d_in[19]; const float* bl2 = (const float*)d_in[20];
  const float* wc1 = (const float*)d_in[21]; const float* bc1 = (const float*)d_in[22];
  const float* wc2 = (const float*)d_in[23]; const float* bc2 = (const float*)d_in[24];
  float* ws  = (float*)d_ws;
  float* out = (float*)d_out;

  prep_k<<<295, 256, 0, stream>>>(ew1, ew2, ew3, ws);
  conv1_k<<<2304, 256, 0, stream>>>(lr, ws + WT1, eb1, ws + T1);
  conv64_k<<<dim3(144,4), 256, 0, stream>>>(ws + T1, ws + WT2, eb2, ws + T2, 1);
  // T1 now dead -> pack heavy+light weights into it as bf16 fragments
  prep_b<<<652, 256, 0, stream>>>(wh1, wh2, wh3, wh4, wl1, wl2, (u16*)(ws + T1));
  conv64_k<<<dim3(144,4), 256, 0, stream>>>(ws + T2, ws + WT3, eb3, ws + FEAT, 0);
  // T2 now dead -> GSVo region
  cls_light_k<<<1152, 256, 0, stream>>>(ws, lr, coord, cell,
                                        wc1, bc1, wc2, bc2, out);
  heavy_k<<<1152, 1024, 0, stream>>>(ws, coord, cell, bh1, bh2, bh3, bh4, bl1, bl2);
  refine_k<<<576, 256, 0, stream>>>(ws, out);
}

// Round 23
// 166.931 us; speedup vs baseline: 1.4670x; 1.0534x over previous
//
#include <hip/hip_runtime.h>

typedef unsigned short u16;
typedef __attribute__((ext_vector_type(8))) short bf16x8;
typedef __attribute__((ext_vector_type(4))) float f32x4;

// ---------- ws layout (float offsets) ----------
enum : int {
  WT1 = 0,          // [27][64]   conv1 weights transposed
  WT2 = 1728,       // [576][64]
  WT3 = 38592,      // [576][64]
  T1  = 75456,      // [9216][64] conv1 out; later bf16 weight frags
  T2  = 665280,     // [9216][64] conv2 out; later GSV
  FEAT= 1255104,    // [9216][64] conv3 out
  PREDP=1844928,    // [3][147456] pre-refine pred planes
  FLAGP=2287296,    // [147456]
  WS_END = 2434752  // 9.74 MB (proven footprint)
};
enum : int { GSVo = T2 };   // [147456][3] grid-sample values (T2 dead after conv3)
// bf16 weight fragments, u16 offsets relative to (u16*)(ws + T1)
enum : int { HB1o = 0, HB2o = 24576, HB3o = 90112, HB4o = 155648,
             LB1o = 159744, LB2o = 165888, HB_TOT = 166912 };

#define QTOT 147456

__device__ __forceinline__ u16 f2b(float f){
  union { float f; unsigned int i; } v; v.f = f;
  unsigned int x = v.i;
  x += 0x7fffu + ((x >> 16) & 1u);   // RNE
  return (u16)(x >> 16);
}
__device__ __forceinline__ unsigned cvtpk(float lo, float hi){
  unsigned r; asm("v_cvt_pk_bf16_f32 %0, %1, %2" : "=v"(r) : "v"(lo), "v"(hi)); return r;
}
union Frag { uint4 u; bf16x8 h; };
__device__ __forceinline__ f32x4 MF(bf16x8 a, bf16x8 b, f32x4 c){
  return __builtin_amdgcn_mfma_f32_16x16x32_bf16(a, b, c, 0, 0, 0);
}

// ---------- prep: conv weight transpose ----------
__global__ __launch_bounds__(256) void prep_k(
    const float* __restrict__ ew1, const float* __restrict__ ew2,
    const float* __restrict__ ew3, float* __restrict__ ws)
{
  int t = blockIdx.x * 256 + threadIdx.x;
  if (t < 1728){ int co=t/27,  r=t-co*27;  ws[WT1 + r*64 + co] = ew1[t]; return; } t -= 1728;
  if (t < 36864){ int co=t/576, r=t-co*576; ws[WT2 + r*64 + co] = ew2[t]; return; } t -= 36864;
  if (t < 36864){ int co=t/576, r=t-co*576; ws[WT3 + r*64 + co] = ew3[t]; return; }
}

// ---------- prep_b: heavy + light MLP weights -> bf16 MFMA fragment layout ----------
__global__ __launch_bounds__(256) void prep_b(
    const float* __restrict__ wh1, const float* __restrict__ wh2,
    const float* __restrict__ wh3, const float* __restrict__ wh4,
    const float* __restrict__ wl1, const float* __restrict__ wl2,
    u16* __restrict__ hb)
{
  int t = blockIdx.x * 256 + threadIdx.x;
  if (t < 24576){   // HB1: 16 nt x 3 kt (K=68 padded to 96)
    int i = t&7, lane = (t>>3)&63, g = t>>9, kt = g%3, nt = g/3;
    int k = kt*32 + (lane>>4)*8 + i, n = nt*16 + (lane&15);
    hb[HB1o + t] = f2b(k < 68 ? wh1[k*256 + n] : 0.f); return;
  } t -= 24576;
  if (t < 65536){   // HB2: 16 nt x 8 kt
    int i = t&7, lane = (t>>3)&63, g = t>>9, kt = g&7, nt = g>>3;
    int k = kt*32 + (lane>>4)*8 + i, n = nt*16 + (lane&15);
    hb[HB2o + t] = f2b(wh2[k*256 + n]); return;
  } t -= 65536;
  if (t < 65536){   // HB3
    int i = t&7, lane = (t>>3)&63, g = t>>9, kt = g&7, nt = g>>3;
    int k = kt*32 + (lane>>4)*8 + i, n = nt*16 + (lane&15);
    hb[HB3o + t] = f2b(wh3[k*256 + n]); return;
  } t -= 65536;
  if (t < 4096){    // HB4: 1 nt (N=3 padded to 16) x 8 kt
    int i = t&7, lane = (t>>3)&63, kt = t>>9;
    int k = kt*32 + (lane>>4)*8 + i, n = lane&15;
    hb[HB4o + t] = f2b(n < 3 ? wh4[k*3 + n] : 0.f); return;
  } t -= 4096;
  if (t < 6144){    // LB1: 4 nt x 3 kt (K=68 padded to 96), light hidden
    int i = t&7, lane = (t>>3)&63, g = t>>9, kt = g%3, nt = g/3;
    int k = kt*32 + (lane>>4)*8 + i, n = nt*16 + (lane&15);
    hb[LB1o + t] = f2b(k < 68 ? wl1[k*64 + n] : 0.f); return;
  } t -= 6144;
  if (t < 1024){    // LB2: 1 nt (N=3 pad 16) x 2 kt, light out
    int i = t&7, lane = (t>>3)&63, kt = t>>9;
    int k = kt*32 + (lane>>4)*8 + i, n = lane&15;
    hb[LB2o + t] = f2b(n < 3 ? wl2[k*3 + n] : 0.f); return;
  }
}

// ---------- conv1: 3 -> 64, relu ----------
__global__ __launch_bounds__(256) void conv1_k(const float* __restrict__ lr, const float* __restrict__ wt1,
                                               const float* __restrict__ b1, float* __restrict__ out)
{
  int t  = threadIdx.x;
  int px = blockIdx.x * 4 + (t >> 6);
  int co = t & 63;
  int y = px / 96, x = px - y * 96;
  float acc = b1[co];
  #pragma unroll
  for (int dy = -1; dy <= 1; ++dy){
    int ny = y + dy; if (ny < 0 || ny > 95) continue;
    #pragma unroll
    for (int dx = -1; dx <= 1; ++dx){
      int nx = x + dx; if (nx < 0 || nx > 95) continue;
      int tap = (dy+1)*3 + (dx+1);
      #pragma unroll
      for (int ci = 0; ci < 3; ++ci)
        acc += lr[ci*9216 + ny*96 + nx] * wt1[(ci*9 + tap)*64 + co];
    }
  }
  out[px*64 + co] = fmaxf(acc, 0.f);
}

// ---------- conv 64->64, LDS-staged weight quarter (r17, proven) ----------
__global__ __launch_bounds__(256, 4) void conv64_k(const float* __restrict__ in, const float* __restrict__ wt,
                                                   const float* __restrict__ bias, float* __restrict__ out, int relu)
{
  __shared__ float wL[576*16];   // 36.9 KB
  int t  = threadIdx.x;
  const int coB = blockIdx.y * 16;

  for (int i = t; i < 9216; i += 256)
    wL[i] = wt[(i >> 4) * 64 + coB + (i & 15)];
  __syncthreads();

  int px = blockIdx.x * 64 + (t >> 2);
  int col = (t & 3) * 4;
  int co  = coB + col;
  int y = px / 96, x = px - y * 96;
  float4 acc = *(const float4*)(bias + co);
  #pragma unroll
  for (int dy = -1; dy <= 1; ++dy){
    int ny = y + dy; if (ny < 0 || ny > 95) continue;
    #pragma unroll
    for (int dx = -1; dx <= 1; ++dx){
      int nx = x + dx; if (nx < 0 || nx > 95) continue;
      int tap = (dy+1)*3 + (dx+1);
      const float* ip = in + (ny*96 + nx)*64;
      const float* wp = wL + tap*16 + col;
      #pragma unroll 4
      for (int c4 = 0; c4 < 16; ++c4){
        float4 iv = *(const float4*)(ip + c4*4);
        float4 w0 = *(const float4*)(wp + (c4*4+0)*144);
        float4 w1 = *(const float4*)(wp + (c4*4+1)*144);
        float4 w2 = *(const float4*)(wp + (c4*4+2)*144);
        float4 w3 = *(const float4*)(wp + (c4*4+3)*144);
        acc.x += iv.x*w0.x + iv.y*w1.x + iv.z*w2.x + iv.w*w3.x;
        acc.y += iv.x*w0.y + iv.y*w1.y + iv.z*w2.y + iv.w*w3.y;
        acc.z += iv.x*w0.z + iv.y*w1.z + iv.z*w2.z + iv.w*w3.z;
        acc.w += iv.x*w0.w + iv.y*w1.w + iv.z*w2.w + iv.w*w3.w;
      }
    }
  }
  if (relu){
    acc.x = fmaxf(acc.x, 0.f); acc.y = fmaxf(acc.y, 0.f);
    acc.z = fmaxf(acc.z, 0.f); acc.w = fmaxf(acc.w, 0.f);
  }
  *(float4*)(out + px*64 + co) = acc;
}

// ---------- K1: gather + f32 classifier + grid sample (r22, proven) ----------
__global__ __launch_bounds__(256, 2) void cls_light_k(float* __restrict__ ws,
    const float* __restrict__ lr, const float* __restrict__ coord, const float* __restrict__ cell,
    const float* __restrict__ wc1, const float* __restrict__ bc1,
    const float* __restrict__ wc2, const float* __restrict__ bc2,
    float* __restrict__ dout)
{
  __shared__ float inpf[128][76];
  __shared__ float wLc1[68*64];
  __shared__ float wLc2[128];
  const float* feat = ws + FEAT;
  const int t = threadIdx.x;
  const int q0 = blockIdx.x * 128;

  for (int i = t; i < 4352; i += 256) wLc1[i] = wc1[i];
  if (t < 128) wLc2[t] = wc2[t];

  {
    int q = t >> 1, part = t & 1, gq = q0 + q;
    float cy = coord[gq*2+0], cx = coord[gq*2+1];
    int iy = (int)floorf((cy + 1.f) * 0.5f * 96.f); iy = iy < 0 ? 0 : (iy > 95 ? 95 : iy);
    int ix = (int)floorf((cx + 1.f) * 0.5f * 96.f); ix = ix < 0 ? 0 : (ix > 95 ? 95 : ix);
    const float* fp = feat + (iy*96 + ix)*64 + part*32;
    #pragma unroll
    for (int s = 0; s < 8; ++s)
      *(float4*)&inpf[q][part*32 + s*4] = *(const float4*)(fp + s*4);
    if (part == 0){
      float fy = -1.f + (2.f*(float)iy + 1.f) / 96.f;
      float fx = -1.f + (2.f*(float)ix + 1.f) / 96.f;
      inpf[q][64] = (cy - fy) * 96.f;
      inpf[q][65] = (cx - fx) * 96.f;
      inpf[q][66] = cell[gq*2 + 0] * 96.f;
      inpf[q][67] = cell[gq*2 + 1] * 96.f;
    }
  }
  __syncthreads();

  // ---- classifier (op order bit-identical to r12-r22 — flag path frozen) ----
  {
    int q = t >> 1, p = t & 1, j0 = p*32;
    float a[32];
    #pragma unroll
    for (int j = 0; j < 32; ++j) a[j] = bc1[j0 + j];
    #pragma unroll 4
    for (int k = 0; k < 68; ++k){
      float xv = inpf[q][k];
      #pragma unroll
      for (int j = 0; j < 32; ++j) a[j] += xv * wLc1[k*64 + j0 + j];
    }
    float l0 = p ? 0.f : bc2[0], l1 = p ? 0.f : bc2[1];
    #pragma unroll
    for (int j = 0; j < 32; ++j){
      float v = fmaxf(a[j], 0.f);
      l0 += v * wLc2[(j0+j)*2]; l1 += v * wLc2[(j0+j)*2 + 1];
    }
    l0 += __shfl_xor(l0, 1); l1 += __shfl_xor(l1, 1);
    if (p == 0){
      float f = (l1 > l0) ? 1.f : 0.f;
      ws[FLAGP + q0 + q] = f; dout[3*QTOT + q0 + q] = f;
    }
  }

  // ---- grid sample (writes GSVo only) ----
  if ((t & 1) == 0){
    int q = t >> 1, gq = q0 + q;
    float cy = coord[gq*2], cx = coord[gq*2 + 1];
    float fy = fminf(fmaxf((cy + 1.f) * 96.f / 2.f - 0.5f, 0.f), 95.f);
    float fx = fminf(fmaxf((cx + 1.f) * 96.f / 2.f - 0.5f, 0.f), 95.f);
    float y0f = floorf(fy), x0f = floorf(fx);
    float wy = fy - y0f, wx = fx - x0f;
    int y0 = (int)y0f, x0 = (int)x0f;
    int y1 = y0 + 1 > 95 ? 95 : y0 + 1;
    int x1 = x0 + 1 > 95 ? 95 : x0 + 1;
    #pragma unroll
    for (int c = 0; c < 3; ++c){
      const float* lp = lr + c*9216;
      float v = lp[y0*96+x0]*(1.f-wy)*(1.f-wx) + lp[y0*96+x1]*(1.f-wy)*wx
              + lp[y1*96+x0]*wy*(1.f-wx) + lp[y1*96+x1]*wy*wx;
      ws[GSVo + gq*3 + c] = v;
    }
  }
}

// ---------- in-place heavy layer (r21, proven) ----------
__device__ __forceinline__ void layerIP(char* buf, const uint4* __restrict__ W,
                                        const float* __restrict__ bias,
                                        int mbase, int nb2, int lrow, int lkg, int lane)
{
  Frag w[2][8];
  #pragma unroll
  for (int j = 0; j < 2; ++j)
    #pragma unroll
    for (int kt = 0; kt < 8; ++kt)
      w[j][kt].u = W[((nb2+j)*8 + kt)*64 + lane];
  f32x4 acc[4][2];
  #pragma unroll
  for (int j = 0; j < 2; ++j){
    float4 bb = *(const float4*)(bias + (nb2+j)*16 + lkg*4);
    #pragma unroll
    for (int mt = 0; mt < 4; ++mt) acc[mt][j] = f32x4{bb.x, bb.y, bb.z, bb.w};
  }
  #pragma unroll
  for (int kt = 0; kt < 8; ++kt){
    #pragma unroll
    for (int mt = 0; mt < 4; ++mt){
      int m = mbase + mt*16 + lrow;
      Frag a; a.u = *(const uint4*)(buf + ((m*512 + kt*64 + lkg*16) ^ ((m&7)<<4)));
      acc[mt][0] = MF(w[0][kt].h, a.h, acc[mt][0]);
      acc[mt][1] = MF(w[1][kt].h, a.h, acc[mt][1]);
    }
  }
  __syncthreads();
  #pragma unroll
  for (int mt = 0; mt < 4; ++mt){
    int m = mbase + mt*16 + lrow;
    #pragma unroll
    for (int j = 0; j < 2; ++j){
      f32x4 v = acc[mt][j];
      uint2 hw = make_uint2(cvtpk(fmaxf(v[0],0.f), fmaxf(v[1],0.f)),
                            cvtpk(fmaxf(v[2],0.f), fmaxf(v[3],0.f)));
      *(uint2*)(buf + ((m*512 + (nb2+j)*32 + lkg*8) ^ ((m&7)<<4))) = hw;
    }
  }
  __syncthreads();
}

// ---------- K2: heavy MLP + light MLP, 128 queries/block, 16 waves ----------
// r23: L1 gather staged ONCE in LDS (was 8x duplicated across n-waves).
__global__ __launch_bounds__(1024, 4) void heavy_k(float* __restrict__ ws,
    const float* __restrict__ coord, const float* __restrict__ cell,
    const float* __restrict__ bh1, const float* __restrict__ bh2,
    const float* __restrict__ bh3, const float* __restrict__ bh4,
    const float* __restrict__ bl1, const float* __restrict__ bl2)
{
  __shared__ u16 buf[128*256];      // 64KB heavy activations (first 32KB doubles as A-staging)
  __shared__ u16 lbuf[128*64];      // 16KB light hidden
  char* Hb = (char*)buf;
  char* Lb = (char*)lbuf;

  const float* feat = ws + FEAT;
  const u16* HB = (const u16*)(ws + T1);
  const int t = threadIdx.x;
  const int q0 = blockIdx.x * 128;
  const int lane = t & 63;
  const int wid  = t >> 6;          // 0..15
  const int lrow = lane & 15, lkg = lane >> 4;
  const int wm = wid >> 3, wn = wid & 7;   // wave grid 2m x 8n
  const int mbase = wm * 64, nb2 = wn * 2;

  // ---- phase A: stage gathered A-tile once: [128 rows][128 u16] (256B stride, swizzled) ----
  {
    int rg = lane >> 3, j = lane & 7;
    int r = wid*8 + rg, gq = q0 + r;
    float cy = coord[gq*2+0], cx = coord[gq*2+1];
    int iy = (int)floorf((cy + 1.f) * 0.5f * 96.f); iy = iy < 0 ? 0 : (iy > 95 ? 95 : iy);
    int ix = (int)floorf((cx + 1.f) * 0.5f * 96.f); ix = ix < 0 ? 0 : (ix > 95 ? 95 : ix);
    const float* fp = feat + (iy*96 + ix)*64 + j*8;
    float4 a0 = *(const float4*)(fp), a1 = *(const float4*)(fp + 4);
    int base = r*256;
    *(uint4*)(Hb + ((base + j*16) ^ ((r&7)<<4))) =
        make_uint4(cvtpk(a0.x,a0.y), cvtpk(a0.z,a0.w), cvtpk(a1.x,a1.y), cvtpk(a1.z,a1.w));
    if (j < 4){
      uint4 z = make_uint4(0,0,0,0);
      if (j == 0){
        float fy = -1.f + (2.f*(float)iy + 1.f) / 96.f;
        float fx = -1.f + (2.f*(float)ix + 1.f) / 96.f;
        z.x = cvtpk((cy - fy) * 96.f, (cx - fx) * 96.f);
        z.y = cvtpk(cell[gq*2 + 0] * 96.f, cell[gq*2 + 1] * 96.f);
      }
      *(uint4*)(Hb + ((base + (8 + j)*16) ^ ((r&7)<<4))) = z;
    }
  }
  __syncthreads();

  // ---- phase B: heavy layer 1 from staged A (values/order identical to r22) ----
  {
    const uint4* W1 = (const uint4*)(HB + HB1o);
    Frag w[2][3];
    #pragma unroll
    for (int j = 0; j < 2; ++j)
      #pragma unroll
      for (int kt = 0; kt < 3; ++kt)
        w[j][kt].u = W1[((nb2+j)*3 + kt)*64 + lane];
    f32x4 acc[4][2];
    #pragma unroll
    for (int j = 0; j < 2; ++j){
      float4 bb = *(const float4*)(bh1 + (nb2+j)*16 + lkg*4);
      #pragma unroll
      for (int mt = 0; mt < 4; ++mt) acc[mt][j] = f32x4{bb.x, bb.y, bb.z, bb.w};
    }
    #pragma unroll
    for (int kt = 0; kt < 3; ++kt)
      #pragma unroll
      for (int mt = 0; mt < 4; ++mt){
        int m = mbase + mt*16 + lrow;
        Frag a; a.u = *(const uint4*)(Hb + ((m*256 + kt*64 + lkg*16) ^ ((m&7)<<4)));
        acc[mt][0] = MF(w[0][kt].h, a.h, acc[mt][0]);
        acc[mt][1] = MF(w[1][kt].h, a.h, acc[mt][1]);
      }
    __syncthreads();   // all staging reads complete before overwrite
    #pragma unroll
    for (int mt = 0; mt < 4; ++mt){
      int m = mbase + mt*16 + lrow;
      #pragma unroll
      for (int j = 0; j < 2; ++j){
        f32x4 v = acc[mt][j];
        uint2 hw = make_uint2(cvtpk(fmaxf(v[0],0.f), fmaxf(v[1],0.f)),
                              cvtpk(fmaxf(v[2],0.f), fmaxf(v[3],0.f)));
        *(uint2*)(Hb + ((m*512 + (nb2+j)*32 + lkg*8) ^ ((m&7)<<4))) = hw;
      }
    }
  }
  __syncthreads();

  // ---- heavy layers 2, 3: in-place ----
  layerIP(Hb, (const uint4*)(HB + HB2o), bh2, mbase, nb2, lrow, lkg, lane);
  layerIP(Hb, (const uint4*)(HB + HB3o), bh3, mbase, nb2, lrow, lkg, lane);

  // ---- concurrent: waves 0-7 heavy L4 (hard preds); waves 8-15 light hidden ----
  if (wid < 8){
    const uint4* W4 = (const uint4*)(HB + HB4o);
    Frag w[8];
    #pragma unroll
    for (int kt = 0; kt < 8; ++kt) w[kt].u = W4[kt*64 + lane];
    f32x4 a4 = f32x4{0.f,0.f,0.f,0.f};
    int m = wid*16 + lrow;
    #pragma unroll
    for (int kt = 0; kt < 8; ++kt){
      Frag a; a.u = *(const uint4*)(Hb + ((m*512 + kt*64 + lkg*16) ^ ((m&7)<<4)));
      a4 = MF(w[kt].h, a.h, a4);
    }
    if (lkg == 0){
      int gq = q0 + m;
      if (ws[FLAGP + gq] > 0.5f){
        #pragma unroll
        for (int r = 0; r < 3; ++r)
          ws[PREDP + r*QTOT + gq] = a4[r] + bh4[r] + ws[GSVo + gq*3 + r];
      }
    }
  } else {
    // light hidden: wave (wid-8) handles 16 rows; all 4 n-tiles
    const uint4* WL1 = (const uint4*)(HB + LB1o);
    int m = (wid - 8)*16 + lrow, gq = q0 + m;
    float cy = coord[gq*2+0], cx = coord[gq*2+1];
    int iy = (int)floorf((cy + 1.f) * 0.5f * 96.f); iy = iy < 0 ? 0 : (iy > 95 ? 95 : iy);
    int ix = (int)floorf((cx + 1.f) * 0.5f * 96.f); ix = ix < 0 ? 0 : (ix > 95 ? 95 : ix);
    const float* fp = feat + (iy*96 + ix)*64 + lkg*8;
    float4 l0 = *(const float4*)(fp +  0), h0 = *(const float4*)(fp +  4);
    float4 l1 = *(const float4*)(fp + 32), h1 = *(const float4*)(fp + 36);
    Frag bf1[3];
    bf1[0].u = make_uint4(cvtpk(l0.x,l0.y), cvtpk(l0.z,l0.w), cvtpk(h0.x,h0.y), cvtpk(h0.z,h0.w));
    bf1[1].u = make_uint4(cvtpk(l1.x,l1.y), cvtpk(l1.z,l1.w), cvtpk(h1.x,h1.y), cvtpk(h1.z,h1.w));
    uint4 z = make_uint4(0,0,0,0);
    if (lkg == 0){
      float fy = -1.f + (2.f*(float)iy + 1.f) / 96.f;
      float fx = -1.f + (2.f*(float)ix + 1.f) / 96.f;
      float r0 = (cy - fy) * 96.f, r1 = (cx - fx) * 96.f;
      float c0 = cell[gq*2 + 0] * 96.f, c1 = cell[gq*2 + 1] * 96.f;
      z.x = cvtpk(r0, r1); z.y = cvtpk(c0, c1);
    }
    bf1[2].u = z;
    f32x4 lacc[4];
    #pragma unroll
    for (int j = 0; j < 4; ++j){
      float4 bb = *(const float4*)(bl1 + j*16 + lkg*4);
      lacc[j] = f32x4{bb.x, bb.y, bb.z, bb.w};
    }
    #pragma unroll
    for (int kt = 0; kt < 3; ++kt)
      #pragma unroll
      for (int j = 0; j < 4; ++j){
        Frag w; w.u = WL1[(j*3 + kt)*64 + lane];
        lacc[j] = MF(w.h, bf1[kt].h, lacc[j]);
      }
    #pragma unroll
    for (int j = 0; j < 4; ++j){
      f32x4 v = lacc[j];
      uint2 hw = make_uint2(cvtpk(fmaxf(v[0],0.f), fmaxf(v[1],0.f)),
                            cvtpk(fmaxf(v[2],0.f), fmaxf(v[3],0.f)));
      *(uint2*)(Lb + ((m*128 + j*32 + lkg*8) ^ ((m&7)<<4))) = hw;
    }
  }
  __syncthreads();

  // ---- light out: waves 8-15, easy-only store ----
  if (wid >= 8){
    const uint4* WL2 = (const uint4*)(HB + LB2o);
    int m = (wid - 8)*16 + lrow, gq = q0 + m;
    f32x4 la = f32x4{0.f,0.f,0.f,0.f};
    #pragma unroll
    for (int kt = 0; kt < 2; ++kt){
      Frag w; w.u = WL2[kt*64 + lane];
      Frag a; a.u = *(const uint4*)(Lb + ((m*128 + kt*64 + lkg*16) ^ ((m&7)<<4)));
      la = MF(w.h, a.h, la);
    }
    if (lkg == 0 && ws[FLAGP + gq] <= 0.5f){
      #pragma unroll
      for (int r = 0; r < 3; ++r)
        ws[PREDP + r*QTOT + gq] = la[r] + bl2[r] + ws[GSVo + gq*3 + r];
    }
  }
}

// ---------- refinement + f32 store ----------
__global__ __launch_bounds__(256) void refine_k(const float* __restrict__ ws, float* __restrict__ dout)
{
  int q = blockIdx.x * 256 + threadIdx.x;
  const float* predp = ws + PREDP;
  const float* flagp = ws + FLAGP;
  int y = q / 384, x = q - y*384;
  float p0 = predp[q], p1 = predp[QTOT + q], p2 = predp[2*QTOT + q];
  if (y > 0 && y < 383 && x > 0 && x < 383 && flagp[q] == 0.f){
    float fs = 0.f, s0 = 0.f, s1 = 0.f, s2 = 0.f;
    #pragma unroll
    for (int dy = -1; dy <= 1; ++dy){
      #pragma unroll
      for (int dx = -1; dx <= 1; ++dx){
        int nq = q + dy*384 + dx;
        fs += flagp[nq];
        s0 += predp[nq]; s1 += predp[QTOT + nq]; s2 += predp[2*QTOT + nq];
      }
    }
    if (fs > 0.5f){ p0 = s0 / 9.f; p1 = s1 / 9.f; p2 = s2 / 9.f; }
  }
  dout[q*3 + 0] = p0;
  dout[q*3 + 1] = p1;
  dout[q*3 + 2] = p2;
}

extern "C" void kernel_launch(void* const* d_in, const int* in_sizes, int n_in,
                              void* d_out, int out_size, void* d_ws, size_t ws_size,
                              hipStream_t stream)
{
  const float* lr    = (const float*)d_in[0];
  const float* coord = (const float*)d_in[1];
  const float* cell  = (const float*)d_in[2];
  const float* ew1 = (const float*)d_in[3];  const float* eb1 = (const float*)d_in[4];
  const float* ew2 = (const float*)d_in[5];  const float* eb2 = (const float*)d_in[6];
  const float* ew3 = (const float*)d_in[7];  const float* eb3 = (const float*)d_in[8];
  const float* wh1 = (const float*)d_in[9];  const float* bh1 = (const float*)d_in[10];
  const float* wh2 = (const float*)d_in[11]; const float* bh2 = (const float*)d_in[12];
  const float* wh3 = (const float*)d_in[13]; const float* bh3 = (const float*)d_in[14];
  const float* wh4 = (const float*)d_in[15]; const float* bh4 = (const float*)d_in[16];
  const float* wl1 = (const float*)d_in[17]; const float* bl1 = (const float*)d_in[18];
  const float* wl2 = (const float*)d_in[19]; const float* bl2 = (const float*)d_in[20];
  const float* wc1 = (const float*)d_in[21]; const float* bc1 = (const float*)d_in[22];
  const float* wc2 = (const float*)d_in[23]; const float* bc2 = (const float*)d_in[24];
  float* ws  = (float*)d_ws;
  float* out = (float*)d_out;

  prep_k<<<295, 256, 0, stream>>>(ew1, ew2, ew3, ws);
  conv1_k<<<2304, 256, 0, stream>>>(lr, ws + WT1, eb1, ws + T1);
  conv64_k<<<dim3(144,4), 256, 0, stream>>>(ws + T1, ws + WT2, eb2, ws + T2, 1);
  // T1 now dead -> pack heavy+light weights into it as bf16 fragments
  prep_b<<<652, 256, 0, stream>>>(wh1, wh2, wh3, wh4, wl1, wl2, (u16*)(ws + T1));
  conv64_k<<<dim3(144,4), 256, 0, stream>>>(ws + T2, ws + WT3, eb3, ws + FEAT, 0);
  // T2 now dead -> GSVo region
  cls_light_k<<<1152, 256, 0, stream>>>(ws, lr, coord, cell,
                                        wc1, bc1, wc2, bc2, out);
  heavy_k<<<1152, 1024, 0, stream>>>(ws, coord, cell, bh1, bh2, bh3, bh4, bl1, bl2);
  refine_k<<<576, 256, 0, stream>>>(ws, out);
}